// Round 4
// baseline (1659.064 us; speedup 1.0000x reference)
//
#include <hip/hip_runtime.h>

#define NNODES 50000
#define NEG 0.01f
#define BN_EPS 1e-5f

#define BINSZ 128            // dst nodes per bin
#define NBINS 392            // ceil(50000/128)
#define CAPG 8192            // record capacity per bin (mean ~4082)
#define PH1B 64              // phase-1 blocks

typedef __attribute__((ext_vector_type(8))) short bf16x8;
typedef __attribute__((ext_vector_type(4))) float f32x4;

__device__ __forceinline__ float lrelu(float v) { return v >= 0.f ? v : NEG * v; }
__device__ __forceinline__ float bf16f(unsigned short u) { return __uint_as_float((unsigned)u << 16); }
__device__ __forceinline__ unsigned f2bf(float x) {          // RNE
    unsigned u = __float_as_uint(x);
    return (u + 0x7fffu + ((u >> 16) & 1u)) >> 16;
}
__device__ __forceinline__ unsigned packbf(float lo, float hi) {
    unsigned b = __float_as_uint(hi);
    b = (b + 0x7fffu + ((b >> 16) & 1u)) & 0xffff0000u;
    return (f2bf(lo) & 0xffffu) | b;
}

// ---------------- 0. convert x + weights to bf16 ----------------
__global__ __launch_bounds__(256)
void prep_kernel(const float* __restrict__ x, const float* __restrict__ Wrel,
                 const float* __restrict__ Wroot, const float* __restrict__ Wlin,
                 unsigned* __restrict__ xb2, unsigned* __restrict__ wb2)
{
    const int NPX = 3200000;           // float pairs in x
    const int NPW = 24576;             // float pairs in 3 weight mats
    for (int i = blockIdx.x * 256 + threadIdx.x; i < NPX + NPW; i += gridDim.x * 256) {
        if (i < NPX) {
            float2 v = ((const float2*)x)[i];
            xb2[i] = packbf(v.x, v.y);
        } else {
            int j = i - NPX;
            const float* W = (j < 8192) ? Wrel : (j < 16384 ? Wroot : Wlin);
            float2 v = ((const float2*)W)[j & 8191];
            wb2[j] = packbf(v.x, v.y);
        }
    }
}

// ---------------- 1. multisplit: bin edges by dst>>7, full-line flushes ----------------
__global__ __launch_bounds__(256)
void bin_kernel(const int* __restrict__ src, const int* __restrict__ dst,
                int* __restrict__ bcnt, unsigned* __restrict__ recs, int n_edges)
{
    __shared__ __align__(16) unsigned buf[NBINS][64];   // ring per bin
    __shared__ int cnt[NBINS];
    __shared__ int flushed[NBINS];

    const int tid = threadIdx.x;
    for (int t = tid; t < NBINS; t += 256) { cnt[t] = 0; flushed[t] = 0; }
    __syncthreads();

    const int per = (n_edges + PH1B - 1) / PH1B;
    const int begin = blockIdx.x * per;
    const int end = min(begin + per, n_edges);

    for (int base = begin; base < end; base += 256) {
        int i = base + tid;
        if (i < end) {
            int s = src[i], d = dst[i];
            int b = d >> 7;
            unsigned rec = (unsigned)s | ((unsigned)(d & 127) << 16);
            int pos = atomicAdd(&cnt[b], 1);
            buf[b][pos & 63] = rec;
        }
        __syncthreads();
        for (int t = tid; t < NBINS; t += 256) {
            int c = cnt[t];
            int f = flushed[t];
            while (c - f >= 16) {                    // 16 recs = 64B = 1 line
                int gbase = atomicAdd(&bcnt[t], 16);
                unsigned* dp = recs + (long)t * CAPG + gbase;
                int ro = f & 63;                     // multiple of 16, no wrap
                #pragma unroll
                for (int k = 0; k < 4; ++k)
                    *(uint4*)(dp + k * 4) = *(uint4*)&buf[t][ro + k * 4];
                f += 16;
            }
            flushed[t] = f;
        }
        __syncthreads();
    }
    // drain leftovers (<16 per bin per block)
    for (int t = tid; t < NBINS; t += 256) {
        int c = cnt[t], f = flushed[t];
        int n = c - f;
        if (n > 0) {
            int gbase = atomicAdd(&bcnt[t], n);
            unsigned* dp = recs + (long)t * CAPG + gbase;
            int ro = f & 63;
            for (int k = 0; k < n; ++k) dp[k] = buf[t][ro + k];
        }
    }
}

// ---------------- 2. per-bin LDS fp32 accumulate -> bf16 agg ----------------
// One block per bin. acc[128 nodes][128 ch] fp32 = 64KB LDS. Lane l handles
// channels l and l+64 -> ds_add_f32 2-way bank alias (free). 8-deep SW pipeline.
__global__ __launch_bounds__(256)
void agg_kernel(const unsigned short* __restrict__ xb, const unsigned* __restrict__ recs,
                const int* __restrict__ bcnt, unsigned short* __restrict__ aggb)
{
    __shared__ __align__(16) float acc[BINSZ * 128];
    const int bin = blockIdx.x;
    const int tid = threadIdx.x;
    const int l = tid & 63, w = tid >> 6;

    #pragma unroll
    for (int i = 0; i < 16; ++i)
        *(float4*)&acc[(tid + i * 256) * 4] = make_float4(0.f, 0.f, 0.f, 0.f);
    __syncthreads();

    const int n = bcnt[bin];
    const unsigned* rp = recs + (long)bin * CAPG;
    const int per = (n + 3) >> 2;
    const int s0 = w * per;
    const int s1 = min(s0 + per, n);

    for (int base = s0; base < s1; base += 64) {
        const int rem = s1 - base;
        const int mm = rem < 64 ? rem : 64;
        unsigned myrec = (base + l < s1) ? rp[base + l] : 0u;

        unsigned pa[8]; unsigned short qa0[8], qa1[8];
        #pragma unroll
        for (int k = 0; k < 8; ++k) {
            unsigned r = __shfl(myrec, k);
            pa[k] = r;
            int s = r & 0xffff;
            qa0[k] = xb[s * 128 + l];
            qa1[k] = xb[s * 128 + 64 + l];
        }
        #pragma unroll
        for (int g = 0; g < 8; ++g) {
            unsigned pb[8]; unsigned short qb0[8], qb1[8];
            if (g < 7) {
                #pragma unroll
                for (int k = 0; k < 8; ++k) {
                    unsigned r = __shfl(myrec, (g + 1) * 8 + k);
                    pb[k] = r;
                    int s = r & 0xffff;
                    qb0[k] = xb[s * 128 + l];
                    qb1[k] = xb[s * 128 + 64 + l];
                }
            }
            #pragma unroll
            for (int k = 0; k < 8; ++k) {
                if (g * 8 + k < mm) {
                    int lo = (pa[k] >> 16) & 127;
                    __hip_atomic_fetch_add(&acc[lo * 128 + l], bf16f(qa0[k]),
                                           __ATOMIC_RELAXED, __HIP_MEMORY_SCOPE_WORKGROUP);
                    __hip_atomic_fetch_add(&acc[lo * 128 + 64 + l], bf16f(qa1[k]),
                                           __ATOMIC_RELAXED, __HIP_MEMORY_SCOPE_WORKGROUP);
                }
            }
            if (g < 7) {
                #pragma unroll
                for (int k = 0; k < 8; ++k) { pa[k] = pb[k]; qa0[k] = qb0[k]; qa1[k] = qb1[k]; }
            }
        }
    }
    __syncthreads();

    // write bf16 agg rows (overwrites this bin's own record region — safe:
    // all reads of rp completed above; region is private to this block)
    const int n0 = bin << 7;
    unsigned* ao = (unsigned*)aggb;
    #pragma unroll
    for (int i = 0; i < (BINSZ * 64) / 256; ++i) {
        int idx = tid + i * 256;
        int node = idx >> 6, cu = idx & 63;
        float f0 = acc[node * 128 + cu * 2];
        float f1 = acc[node * 128 + cu * 2 + 1];
        ao[(long)(n0 + node) * 64 + cu] = packbf(f0, f1);
    }
}

// ---------------- 3. MFMA MLP (unchanged from R3) ----------------
__global__ __launch_bounds__(256)
void mlp_mfma_kernel(const unsigned short* __restrict__ aggb, const unsigned short* __restrict__ xb,
                     const unsigned short* __restrict__ wb,
                     const float* __restrict__ brel, const float* __restrict__ blin,
                     float* __restrict__ out, float* __restrict__ sums, float* __restrict__ sumsq)
{
    __shared__ unsigned short smx2[32][136];

    const int tid = threadIdx.x;
    const int w = tid >> 6;
    const int l = tid & 63;
    const int l15 = l & 15;
    const int kg = l >> 4;
    const int n0 = blockIdx.x * 32;

    const unsigned short* Wrelb  = wb;
    const unsigned short* Wrootb = wb + 16384;
    const unsigned short* Wlinb  = wb + 32768;

    const int rA0 = n0 + l15, rA1 = n0 + 16 + l15;
    const long cA0 = min(rA0, NNODES - 1), cA1 = min(rA1, NNODES - 1);
    const int rB0 = w * 32 + l15, rB1 = rB0 + 16;

    f32x4 acc00 = {0.f,0.f,0.f,0.f}, acc01 = acc00, acc10 = acc00, acc11 = acc00;

    #pragma unroll
    for (int s = 0; s < 8; ++s) {
        const unsigned short* Ab = (s < 4) ? aggb : xb;
        const unsigned short* Bb = (s < 4) ? Wrelb : Wrootb;
        const int ko = (s & 3) * 32 + kg * 8;
        bf16x8 a0 = *(const bf16x8*)(Ab + cA0 * 128 + ko);
        bf16x8 a1 = *(const bf16x8*)(Ab + cA1 * 128 + ko);
        bf16x8 b0 = *(const bf16x8*)(Bb + rB0 * 128 + ko);
        bf16x8 b1 = *(const bf16x8*)(Bb + rB1 * 128 + ko);
        acc00 = __builtin_amdgcn_mfma_f32_16x16x32_bf16(a0, b0, acc00, 0, 0, 0);
        acc01 = __builtin_amdgcn_mfma_f32_16x16x32_bf16(a0, b1, acc01, 0, 0, 0);
        acc10 = __builtin_amdgcn_mfma_f32_16x16x32_bf16(a1, b0, acc10, 0, 0, 0);
        acc11 = __builtin_amdgcn_mfma_f32_16x16x32_bf16(a1, b1, acc11, 0, 0, 0);
    }

    {
        const float br0 = brel[rB0], br1 = brel[rB1];
        const int mr = kg * 4;
        #pragma unroll
        for (int r = 0; r < 4; ++r) {
            smx2[mr + r][rB0]      = (unsigned short)f2bf(lrelu(acc00[r] + br0));
            smx2[mr + r][rB1]      = (unsigned short)f2bf(lrelu(acc01[r] + br1));
            smx2[16 + mr + r][rB0] = (unsigned short)f2bf(lrelu(acc10[r] + br0));
            smx2[16 + mr + r][rB1] = (unsigned short)f2bf(lrelu(acc11[r] + br1));
        }
    }
    __syncthreads();

    f32x4 o00 = {0.f,0.f,0.f,0.f}, o01 = o00, o10 = o00, o11 = o00;
    #pragma unroll
    for (int s = 0; s < 4; ++s) {
        const int ko = s * 32 + kg * 8;
        bf16x8 a0 = *(const bf16x8*)(&smx2[l15][ko]);
        bf16x8 a1 = *(const bf16x8*)(&smx2[16 + l15][ko]);
        bf16x8 b0 = *(const bf16x8*)(Wlinb + rB0 * 128 + ko);
        bf16x8 b1 = *(const bf16x8*)(Wlinb + rB1 * 128 + ko);
        o00 = __builtin_amdgcn_mfma_f32_16x16x32_bf16(a0, b0, o00, 0, 0, 0);
        o01 = __builtin_amdgcn_mfma_f32_16x16x32_bf16(a0, b1, o01, 0, 0, 0);
        o10 = __builtin_amdgcn_mfma_f32_16x16x32_bf16(a1, b0, o10, 0, 0, 0);
        o11 = __builtin_amdgcn_mfma_f32_16x16x32_bf16(a1, b1, o11, 0, 0, 0);
    }

    const float bl0 = blin[rB0], bl1 = blin[rB1];
    float ps0 = 0.f, pq0 = 0.f, ps1 = 0.f, pq1 = 0.f;
    const int mr = kg * 4;
    #pragma unroll
    for (int mi = 0; mi < 2; ++mi) {
        f32x4 v0 = mi ? o10 : o00;
        f32x4 v1 = mi ? o11 : o01;
        #pragma unroll
        for (int r = 0; r < 4; ++r) {
            int m = n0 + mi * 16 + mr + r;
            if (m < NNODES) {
                float y0 = v0[r] + bl0;
                float y1 = v1[r] + bl1;
                out[(long)m * 128 + rB0] = y0;
                out[(long)m * 128 + rB1] = y1;
                ps0 += y0; pq0 += y0 * y0;
                ps1 += y1; pq1 += y1 * y1;
            }
        }
    }
    ps0 += __shfl_xor(ps0, 16); ps0 += __shfl_xor(ps0, 32);
    pq0 += __shfl_xor(pq0, 16); pq0 += __shfl_xor(pq0, 32);
    ps1 += __shfl_xor(ps1, 16); ps1 += __shfl_xor(ps1, 32);
    pq1 += __shfl_xor(pq1, 16); pq1 += __shfl_xor(pq1, 32);
    if (kg == 0) {
        atomicAdd(&sums[rB0], ps0);  atomicAdd(&sumsq[rB0], pq0);
        atomicAdd(&sums[rB1], ps1);  atomicAdd(&sumsq[rB1], pq1);
    }
}

// ---------------- 4. BN finalize ----------------
__global__ void bn_final_kernel(const float* __restrict__ sums, const float* __restrict__ sumsq,
                                const float* __restrict__ gamma, const float* __restrict__ beta,
                                float* __restrict__ ss)
{
    int h = threadIdx.x;
    float mean = sums[h] * (1.f / NNODES);
    float var = sumsq[h] * (1.f / NNODES) - mean * mean;
    float sc = gamma[h] * rsqrtf(var + BN_EPS);
    ss[h] = sc;
    ss[128 + h] = beta[h] - mean * sc;
}

// ---------------- 5. BN apply + leaky ----------------
__global__ __launch_bounds__(256)
void bn_apply_kernel(float* __restrict__ out, const float* __restrict__ ss)
{
    __shared__ float s_sc[128], s_sh[128];
    if (threadIdx.x < 128) {
        s_sc[threadIdx.x] = ss[threadIdx.x];
        s_sh[threadIdx.x] = ss[128 + threadIdx.x];
    }
    __syncthreads();
    const int total = NNODES * 32;
    float4* o4 = (float4*)out;
    for (int i = blockIdx.x * 256 + threadIdx.x; i < total; i += gridDim.x * 256) {
        float4 v = o4[i];
        int h = (i & 31) * 4;
        v.x = lrelu(v.x * s_sc[h + 0] + s_sh[h + 0]);
        v.y = lrelu(v.y * s_sc[h + 1] + s_sh[h + 1]);
        v.z = lrelu(v.z * s_sc[h + 2] + s_sh[h + 2]);
        v.w = lrelu(v.w * s_sc[h + 3] + s_sh[h + 3]);
        o4[i] = v;
    }
}

extern "C" void kernel_launch(void* const* d_in, const int* in_sizes, int n_in,
                              void* d_out, int out_size, void* d_ws, size_t ws_size,
                              hipStream_t stream)
{
    const float* x     = (const float*)d_in[0];
    const int*   ei    = (const int*)d_in[1];
    const float* Wrel  = (const float*)d_in[3];
    const float* brel  = (const float*)d_in[4];
    const float* Wroot = (const float*)d_in[5];
    const float* Wlin  = (const float*)d_in[6];
    const float* blin  = (const float*)d_in[7];
    const float* gamma = (const float*)d_in[8];
    const float* beta  = (const float*)d_in[9];
    float* out = (float*)d_out;

    const int n_edges = in_sizes[1] / 2;
    const int* src = ei;
    const int* dst = ei + n_edges;

    // workspace layout (bytes):
    // xb        @ 0          : 12,800,000   (x as bf16)
    // recs∪aggb @ 12,800,000 : 12,845,056   (NBINS*CAPG*4; aggb bf16 aliases linearly)
    // wb        @ 25,645,056 : 98,304
    // bcnt      @ 25,743,360 : 1,568        } memset together (3,616 B)
    // stats     @ 25,744,928 : 2,048        }
    char* ws = (char*)d_ws;
    unsigned short* xb   = (unsigned short*)ws;
    unsigned*       recs = (unsigned*)(ws + 12800000);
    unsigned short* aggb = (unsigned short*)(ws + 12800000);
    unsigned short* wb   = (unsigned short*)(ws + 25645056);
    int*   bcnt  = (int*)(ws + 25743360);
    float* sums  = (float*)(ws + 25744928);
    float* sumsq = sums + 128;
    float* ss    = sums + 256;

    hipMemsetAsync(bcnt, 0, 3616, stream);   // bcnt + stats

    prep_kernel<<<4096, 256, 0, stream>>>(x, Wrel, Wroot, Wlin, (unsigned*)xb, (unsigned*)wb);
    bin_kernel<<<PH1B, 256, 0, stream>>>(src, dst, bcnt, recs, n_edges);
    agg_kernel<<<NBINS, 256, 0, stream>>>(xb, recs, bcnt, aggb);
    mlp_mfma_kernel<<<(NNODES + 31) / 32, 256, 0, stream>>>(
        aggb, xb, wb, brel, blin, out, sums, sumsq);
    bn_final_kernel<<<1, 128, 0, stream>>>(sums, sumsq, gamma, beta, ss);
    bn_apply_kernel<<<2048, 256, 0, stream>>>(out, ss);
}

// Round 5
// 1535.445 us; speedup vs baseline: 1.0805x; 1.0805x over previous
//
#include <hip/hip_runtime.h>

#define NNODES 50000
#define NEG 0.01f
#define BN_EPS 1e-5f

#define BINSZ 128            // dst nodes per bin
#define NBINS 392            // ceil(50000/128)
#define CAPG 8192            // record capacity per bin (mean ~4082)
#define PH1B 256             // phase-1 blocks (1 per CU)
#define RING 32              // ring slots per bin (flush granule 16)

typedef __attribute__((ext_vector_type(8))) short bf16x8;
typedef __attribute__((ext_vector_type(4))) float f32x4;

__device__ __forceinline__ float lrelu(float v) { return v >= 0.f ? v : NEG * v; }
__device__ __forceinline__ float bf_lo(unsigned u) { return __uint_as_float(u << 16); }
__device__ __forceinline__ float bf_hi(unsigned u) { return __uint_as_float(u & 0xffff0000u); }
__device__ __forceinline__ unsigned f2bf(float x) {          // RNE
    unsigned u = __float_as_uint(x);
    return (u + 0x7fffu + ((u >> 16) & 1u)) >> 16;
}
__device__ __forceinline__ unsigned packbf(float lo, float hi) {
    unsigned b = __float_as_uint(hi);
    b = (b + 0x7fffu + ((b >> 16) & 1u)) & 0xffff0000u;
    return (f2bf(lo) & 0xffffu) | b;
}

// ---------------- 0. convert x + weights to bf16 ----------------
__global__ __launch_bounds__(256)
void prep_kernel(const float* __restrict__ x, const float* __restrict__ Wrel,
                 const float* __restrict__ Wroot, const float* __restrict__ Wlin,
                 unsigned* __restrict__ xb2, unsigned* __restrict__ wb2)
{
    const int NPX = 3200000;           // float pairs in x
    const int NPW = 24576;             // float pairs in 3 weight mats
    for (int i = blockIdx.x * 256 + threadIdx.x; i < NPX + NPW; i += gridDim.x * 256) {
        if (i < NPX) {
            float2 v = ((const float2*)x)[i];
            xb2[i] = packbf(v.x, v.y);
        } else {
            int j = i - NPX;
            const float* W = (j < 8192) ? Wrel : (j < 16384 ? Wroot : Wlin);
            float2 v = ((const float2*)W)[j & 8191];
            wb2[j] = packbf(v.x, v.y);
        }
    }
}

// ---------------- 1. multisplit: bin edges by dst>>7, line-combined flushes ----------------
__global__ __launch_bounds__(256)
void bin_kernel(const int* __restrict__ src, const int* __restrict__ dst,
                int* __restrict__ bcnt, unsigned* __restrict__ recs, int n_edges)
{
    __shared__ __align__(16) unsigned buf[NBINS][RING];
    __shared__ int cnt[NBINS];
    __shared__ int flushed[NBINS];

    const int tid = threadIdx.x;
    for (int t = tid; t < NBINS; t += 256) { cnt[t] = 0; flushed[t] = 0; }
    __syncthreads();

    const int per = (n_edges + PH1B - 1) / PH1B;
    const int begin = blockIdx.x * per;
    const int end = min(begin + per, n_edges);

    for (int base = begin; base < end; base += 256) {
        int i = base + tid;
        if (i < end) {
            int s = src[i], d = dst[i];
            int b = d >> 7;
            unsigned rec = (unsigned)s | ((unsigned)(d & 127) << 16);
            int pos = atomicAdd(&cnt[b], 1);
            buf[b][pos & (RING - 1)] = rec;
        }
        __syncthreads();
        for (int t = tid; t < NBINS; t += 256) {
            int c = cnt[t];
            int f = flushed[t];
            while (c - f >= 16) {                    // 16 recs = 64B = 1 line
                int gbase = atomicAdd(&bcnt[t], 16);
                unsigned* dp = recs + (long)t * CAPG + gbase;
                int ro = f & (RING - 1);             // multiple of 16, no wrap
                #pragma unroll
                for (int k = 0; k < 4; ++k)
                    *(uint4*)(dp + k * 4) = *(uint4*)&buf[t][ro + k * 4];
                f += 16;
            }
            flushed[t] = f;
        }
        __syncthreads();
    }
    // drain leftovers (<16 per bin per block) — compact via reservation
    for (int t = tid; t < NBINS; t += 256) {
        int c = cnt[t], f = flushed[t];
        int n = c - f;
        if (n > 0) {
            int gbase = atomicAdd(&bcnt[t], n);
            unsigned* dp = recs + (long)t * CAPG + gbase;
            int ro = f & (RING - 1);
            for (int k = 0; k < n; ++k) dp[k] = buf[t][ro + k];
        }
    }
}

// ---------------- 2. per-bin LDS fp32 accumulate -> bf16 agg ----------------
// One block per bin. acc split-channel layout: acc[lo*128 + l] = ch 2l,
// acc[lo*128 + 64 + l] = ch 2l+1  (l = lane 0..63) -> ds_add bank = l%32,
// 2-way alias (free). Per record: 1 uniform rec load + 1 coalesced uint row
// load (256B/wave) + 2 ds_add_f32. 8 independent records in flight.
__global__ __launch_bounds__(256)
void agg_kernel(const unsigned* __restrict__ xb2, const unsigned* __restrict__ recs,
                const int* __restrict__ bcnt, unsigned short* __restrict__ aggb)
{
    __shared__ __align__(16) float acc[BINSZ * 128];
    const int bin = blockIdx.x;
    const int tid = threadIdx.x;
    const int l = tid & 63, w = tid >> 6;

    #pragma unroll
    for (int i = 0; i < 16; ++i)
        *(float4*)&acc[(tid + i * 256) * 4] = make_float4(0.f, 0.f, 0.f, 0.f);
    __syncthreads();

    const int n = bcnt[bin];
    const unsigned* rp = recs + (long)bin * CAPG;
    const int per = (n + 3) >> 2;
    const int r0 = w * per;
    const int r1 = min(r0 + per, n);

    int i = r0;
    for (; i + 8 <= r1; i += 8) {
        unsigned rec[8], q[8];
        #pragma unroll
        for (int k = 0; k < 8; ++k) rec[k] = rp[i + k];
        #pragma unroll
        for (int k = 0; k < 8; ++k) q[k] = xb2[(rec[k] & 0xffffu) * 64 + l];
        #pragma unroll
        for (int k = 0; k < 8; ++k) {
            int lo = (rec[k] >> 16) & 127;
            atomicAdd(&acc[lo * 128 + l],      bf_lo(q[k]));
            atomicAdd(&acc[lo * 128 + 64 + l], bf_hi(q[k]));
        }
    }
    for (; i < r1; ++i) {
        unsigned r = rp[i];
        unsigned q = xb2[(r & 0xffffu) * 64 + l];
        int lo = (r >> 16) & 127;
        atomicAdd(&acc[lo * 128 + l],      bf_lo(q));
        atomicAdd(&acc[lo * 128 + 64 + l], bf_hi(q));
    }
    __syncthreads();

    // de-permute + pack to bf16; overwrites this bin's own record region (all
    // reads completed above; region private to this block)
    const int n0 = bin << 7;
    unsigned* ao = (unsigned*)aggb;
    #pragma unroll
    for (int it = 0; it < (BINSZ * 64) / 256; ++it) {
        int idx = tid + it * 256;
        int node = idx >> 6, c = idx & 63;
        float f0 = acc[node * 128 + c];        // ch 2c
        float f1 = acc[node * 128 + 64 + c];   // ch 2c+1
        ao[(long)(n0 + node) * 64 + c] = packbf(f0, f1);
    }
}

// ---------------- 3. MFMA MLP (unchanged, proven R3/R4) ----------------
__global__ __launch_bounds__(256)
void mlp_mfma_kernel(const unsigned short* __restrict__ aggb, const unsigned short* __restrict__ xb,
                     const unsigned short* __restrict__ wb,
                     const float* __restrict__ brel, const float* __restrict__ blin,
                     float* __restrict__ out, float* __restrict__ sums, float* __restrict__ sumsq)
{
    __shared__ unsigned short smx2[32][136];

    const int tid = threadIdx.x;
    const int w = tid >> 6;
    const int l = tid & 63;
    const int l15 = l & 15;
    const int kg = l >> 4;
    const int n0 = blockIdx.x * 32;

    const unsigned short* Wrelb  = wb;
    const unsigned short* Wrootb = wb + 16384;
    const unsigned short* Wlinb  = wb + 32768;

    const int rA0 = n0 + l15, rA1 = n0 + 16 + l15;
    const long cA0 = min(rA0, NNODES - 1), cA1 = min(rA1, NNODES - 1);
    const int rB0 = w * 32 + l15, rB1 = rB0 + 16;

    f32x4 acc00 = {0.f,0.f,0.f,0.f}, acc01 = acc00, acc10 = acc00, acc11 = acc00;

    #pragma unroll
    for (int s = 0; s < 8; ++s) {
        const unsigned short* Ab = (s < 4) ? aggb : xb;
        const unsigned short* Bb = (s < 4) ? Wrelb : Wrootb;
        const int ko = (s & 3) * 32 + kg * 8;
        bf16x8 a0 = *(const bf16x8*)(Ab + cA0 * 128 + ko);
        bf16x8 a1 = *(const bf16x8*)(Ab + cA1 * 128 + ko);
        bf16x8 b0 = *(const bf16x8*)(Bb + rB0 * 128 + ko);
        bf16x8 b1 = *(const bf16x8*)(Bb + rB1 * 128 + ko);
        acc00 = __builtin_amdgcn_mfma_f32_16x16x32_bf16(a0, b0, acc00, 0, 0, 0);
        acc01 = __builtin_amdgcn_mfma_f32_16x16x32_bf16(a0, b1, acc01, 0, 0, 0);
        acc10 = __builtin_amdgcn_mfma_f32_16x16x32_bf16(a1, b0, acc10, 0, 0, 0);
        acc11 = __builtin_amdgcn_mfma_f32_16x16x32_bf16(a1, b1, acc11, 0, 0, 0);
    }

    {
        const float br0 = brel[rB0], br1 = brel[rB1];
        const int mr = kg * 4;
        #pragma unroll
        for (int r = 0; r < 4; ++r) {
            smx2[mr + r][rB0]      = (unsigned short)f2bf(lrelu(acc00[r] + br0));
            smx2[mr + r][rB1]      = (unsigned short)f2bf(lrelu(acc01[r] + br1));
            smx2[16 + mr + r][rB0] = (unsigned short)f2bf(lrelu(acc10[r] + br0));
            smx2[16 + mr + r][rB1] = (unsigned short)f2bf(lrelu(acc11[r] + br1));
        }
    }
    __syncthreads();

    f32x4 o00 = {0.f,0.f,0.f,0.f}, o01 = o00, o10 = o00, o11 = o00;
    #pragma unroll
    for (int s = 0; s < 4; ++s) {
        const int ko = s * 32 + kg * 8;
        bf16x8 a0 = *(const bf16x8*)(&smx2[l15][ko]);
        bf16x8 a1 = *(const bf16x8*)(&smx2[16 + l15][ko]);
        bf16x8 b0 = *(const bf16x8*)(Wlinb + rB0 * 128 + ko);
        bf16x8 b1 = *(const bf16x8*)(Wlinb + rB1 * 128 + ko);
        o00 = __builtin_amdgcn_mfma_f32_16x16x32_bf16(a0, b0, o00, 0, 0, 0);
        o01 = __builtin_amdgcn_mfma_f32_16x16x32_bf16(a0, b1, o01, 0, 0, 0);
        o10 = __builtin_amdgcn_mfma_f32_16x16x32_bf16(a1, b0, o10, 0, 0, 0);
        o11 = __builtin_amdgcn_mfma_f32_16x16x32_bf16(a1, b1, o11, 0, 0, 0);
    }

    const float bl0 = blin[rB0], bl1 = blin[rB1];
    float ps0 = 0.f, pq0 = 0.f, ps1 = 0.f, pq1 = 0.f;
    const int mr = kg * 4;
    #pragma unroll
    for (int mi = 0; mi < 2; ++mi) {
        f32x4 v0 = mi ? o10 : o00;
        f32x4 v1 = mi ? o11 : o01;
        #pragma unroll
        for (int r = 0; r < 4; ++r) {
            int m = n0 + mi * 16 + mr + r;
            if (m < NNODES) {
                float y0 = v0[r] + bl0;
                float y1 = v1[r] + bl1;
                out[(long)m * 128 + rB0] = y0;
                out[(long)m * 128 + rB1] = y1;
                ps0 += y0; pq0 += y0 * y0;
                ps1 += y1; pq1 += y1 * y1;
            }
        }
    }
    ps0 += __shfl_xor(ps0, 16); ps0 += __shfl_xor(ps0, 32);
    pq0 += __shfl_xor(pq0, 16); pq0 += __shfl_xor(pq0, 32);
    ps1 += __shfl_xor(ps1, 16); ps1 += __shfl_xor(ps1, 32);
    pq1 += __shfl_xor(pq1, 16); pq1 += __shfl_xor(pq1, 32);
    if (kg == 0) {
        atomicAdd(&sums[rB0], ps0);  atomicAdd(&sumsq[rB0], pq0);
        atomicAdd(&sums[rB1], ps1);  atomicAdd(&sumsq[rB1], pq1);
    }
}

// ---------------- 4. BN finalize ----------------
__global__ void bn_final_kernel(const float* __restrict__ sums, const float* __restrict__ sumsq,
                                const float* __restrict__ gamma, const float* __restrict__ beta,
                                float* __restrict__ ss)
{
    int h = threadIdx.x;
    float mean = sums[h] * (1.f / NNODES);
    float var = sumsq[h] * (1.f / NNODES) - mean * mean;
    float sc = gamma[h] * rsqrtf(var + BN_EPS);
    ss[h] = sc;
    ss[128 + h] = beta[h] - mean * sc;
}

// ---------------- 5. BN apply + leaky ----------------
__global__ __launch_bounds__(256)
void bn_apply_kernel(float* __restrict__ out, const float* __restrict__ ss)
{
    __shared__ float s_sc[128], s_sh[128];
    if (threadIdx.x < 128) {
        s_sc[threadIdx.x] = ss[threadIdx.x];
        s_sh[threadIdx.x] = ss[128 + threadIdx.x];
    }
    __syncthreads();
    const int total = NNODES * 32;
    float4* o4 = (float4*)out;
    for (int i = blockIdx.x * 256 + threadIdx.x; i < total; i += gridDim.x * 256) {
        float4 v = o4[i];
        int h = (i & 31) * 4;
        v.x = lrelu(v.x * s_sc[h + 0] + s_sh[h + 0]);
        v.y = lrelu(v.y * s_sc[h + 1] + s_sh[h + 1]);
        v.z = lrelu(v.z * s_sc[h + 2] + s_sh[h + 2]);
        v.w = lrelu(v.w * s_sc[h + 3] + s_sh[h + 3]);
        o4[i] = v;
    }
}

extern "C" void kernel_launch(void* const* d_in, const int* in_sizes, int n_in,
                              void* d_out, int out_size, void* d_ws, size_t ws_size,
                              hipStream_t stream)
{
    const float* x     = (const float*)d_in[0];
    const int*   ei    = (const int*)d_in[1];
    const float* Wrel  = (const float*)d_in[3];
    const float* brel  = (const float*)d_in[4];
    const float* Wroot = (const float*)d_in[5];
    const float* Wlin  = (const float*)d_in[6];
    const float* blin  = (const float*)d_in[7];
    const float* gamma = (const float*)d_in[8];
    const float* beta  = (const float*)d_in[9];
    float* out = (float*)d_out;

    const int n_edges = in_sizes[1] / 2;
    const int* src = ei;
    const int* dst = ei + n_edges;

    // workspace layout (bytes):
    // xb        @ 0          : 12,800,000   (x as bf16)
    // recs∪aggb @ 12,800,000 : 12,845,056   (NBINS*CAPG*4; aggb bf16 aliases linearly)
    // wb        @ 25,645,056 : 98,304
    // bcnt      @ 25,743,360 : 1,568        } memset together (3,616 B)
    // stats     @ 25,744,928 : 2,048        }
    char* ws = (char*)d_ws;
    unsigned short* xb   = (unsigned short*)ws;
    unsigned*       recs = (unsigned*)(ws + 12800000);
    unsigned short* aggb = (unsigned short*)(ws + 12800000);
    unsigned short* wb   = (unsigned short*)(ws + 25645056);
    int*   bcnt  = (int*)(ws + 25743360);
    float* sums  = (float*)(ws + 25744928);
    float* sumsq = sums + 128;
    float* ss    = sums + 256;

    hipMemsetAsync(bcnt, 0, 3616, stream);   // bcnt + stats

    prep_kernel<<<4096, 256, 0, stream>>>(x, Wrel, Wroot, Wlin, (unsigned*)xb, (unsigned*)wb);
    bin_kernel<<<PH1B, 256, 0, stream>>>(src, dst, bcnt, recs, n_edges);
    agg_kernel<<<NBINS, 256, 0, stream>>>((const unsigned*)xb, recs, bcnt, aggb);
    mlp_mfma_kernel<<<(NNODES + 31) / 32, 256, 0, stream>>>(
        aggb, xb, wb, brel, blin, out, sums, sumsq);
    bn_final_kernel<<<1, 128, 0, stream>>>(sums, sumsq, gamma, beta, ss);
    bn_apply_kernel<<<2048, 256, 0, stream>>>(out, ss);
}

// Round 6
// 289.853 us; speedup vs baseline: 5.7238x; 5.2973x over previous
//
#include <hip/hip_runtime.h>

#define NNODES 50000
#define NEG 0.01f
#define BN_EPS 1e-5f

#define BINSZ 128            // dst nodes per bin
#define NBINS 392            // ceil(50000/128)
#define CAPG 8192            // record capacity per bin (mean ~4082)
#define PH1B 256             // phase-1 blocks (1 per CU)
#define RING 32              // ring slots per bin (flush granule 16)

typedef __attribute__((ext_vector_type(8))) short bf16x8;
typedef __attribute__((ext_vector_type(4))) float f32x4;

__device__ __forceinline__ float lrelu(float v) { return v >= 0.f ? v : NEG * v; }
__device__ __forceinline__ float bf_lo(unsigned u) { return __uint_as_float(u << 16); }
__device__ __forceinline__ float bf_hi(unsigned u) { return __uint_as_float(u & 0xffff0000u); }
__device__ __forceinline__ unsigned f2bf(float x) {          // RNE
    unsigned u = __float_as_uint(x);
    return (u + 0x7fffu + ((u >> 16) & 1u)) >> 16;
}
__device__ __forceinline__ unsigned packbf(float lo, float hi) {
    unsigned b = __float_as_uint(hi);
    b = (b + 0x7fffu + ((b >> 16) & 1u)) & 0xffff0000u;
    return (f2bf(lo) & 0xffffu) | b;
}

// ---------------- 0. convert x + weights to bf16 ----------------
__global__ __launch_bounds__(256)
void prep_kernel(const float* __restrict__ x, const float* __restrict__ Wrel,
                 const float* __restrict__ Wroot, const float* __restrict__ Wlin,
                 unsigned* __restrict__ xb2, unsigned* __restrict__ wb2)
{
    const int NPX = 3200000;           // float pairs in x
    const int NPW = 24576;             // float pairs in 3 weight mats
    for (int i = blockIdx.x * 256 + threadIdx.x; i < NPX + NPW; i += gridDim.x * 256) {
        if (i < NPX) {
            float2 v = ((const float2*)x)[i];
            xb2[i] = packbf(v.x, v.y);
        } else {
            int j = i - NPX;
            const float* W = (j < 8192) ? Wrel : (j < 16384 ? Wroot : Wlin);
            float2 v = ((const float2*)W)[j & 8191];
            wb2[j] = packbf(v.x, v.y);
        }
    }
}

// ---------------- 1. multisplit: bin edges by dst>>7, line-combined flushes ----------------
__global__ __launch_bounds__(256)
void bin_kernel(const int* __restrict__ src, const int* __restrict__ dst,
                int* __restrict__ bcnt, unsigned* __restrict__ recs, int n_edges)
{
    __shared__ __align__(16) unsigned buf[NBINS][RING];
    __shared__ int cnt[NBINS];
    __shared__ int flushed[NBINS];

    const int tid = threadIdx.x;
    for (int t = tid; t < NBINS; t += 256) { cnt[t] = 0; flushed[t] = 0; }
    __syncthreads();

    const int per = (n_edges + PH1B - 1) / PH1B;
    const int begin = blockIdx.x * per;
    const int end = min(begin + per, n_edges);

    for (int base = begin; base < end; base += 256) {
        int i = base + tid;
        if (i < end) {
            int s = src[i], d = dst[i];
            int b = d >> 7;
            unsigned rec = (unsigned)s | ((unsigned)(d & 127) << 16);
            int pos = atomicAdd(&cnt[b], 1);
            buf[b][pos & (RING - 1)] = rec;
        }
        __syncthreads();
        for (int t = tid; t < NBINS; t += 256) {
            int c = cnt[t];
            int f = flushed[t];
            while (c - f >= 16) {                    // 16 recs = 64B = 1 line
                int gbase = atomicAdd(&bcnt[t], 16);
                unsigned* dp = recs + (long)t * CAPG + gbase;
                int ro = f & (RING - 1);             // multiple of 16, no wrap
                #pragma unroll
                for (int k = 0; k < 4; ++k)
                    *(uint4*)(dp + k * 4) = *(uint4*)&buf[t][ro + k * 4];
                f += 16;
            }
            flushed[t] = f;
        }
        __syncthreads();
    }
    // drain leftovers (<16 per bin per block) — compact via reservation
    for (int t = tid; t < NBINS; t += 256) {
        int c = cnt[t], f = flushed[t];
        int n = c - f;
        if (n > 0) {
            int gbase = atomicAdd(&bcnt[t], n);
            unsigned* dp = recs + (long)t * CAPG + gbase;
            int ro = f & (RING - 1);
            for (int k = 0; k < n; ++k) dp[k] = buf[t][ro + k];
        }
    }
}

// ---------------- 2. per-bin: counting-sort records, register-accumulate ----------------
// One block per bin. No fp32 LDS atomics. Phase A: int histogram (ds_add_u32)
// + 128-wide scan + scatter records into sorted LDS order. Phase B: each wave
// walks contiguous per-node runs; lane l accumulates channels (2l, 2l+1) in 2
// registers; per record = 1 LDS broadcast read + 1 coalesced 256B row load.
__global__ __launch_bounds__(256)
void agg_kernel(const unsigned* __restrict__ xb2, const unsigned* __restrict__ recs,
                const int* __restrict__ bcnt, unsigned short* __restrict__ aggb)
{
    __shared__ unsigned srec[CAPG];        // 32 KB sorted records
    __shared__ int cnt[BINSZ];
    __shared__ int pos[BINSZ];
    __shared__ int offs[BINSZ + 1];
    __shared__ int sh_w0;

    const int bin = blockIdx.x;
    const int tid = threadIdx.x;
    const int l = tid & 63, w = tid >> 6;

    if (tid < BINSZ) cnt[tid] = 0;
    __syncthreads();

    const int n = bcnt[bin];
    const unsigned* rp = recs + (long)bin * CAPG;

    // A1: histogram by local dst (native int ds atomics)
    for (int i = tid; i < n; i += 256)
        atomicAdd(&cnt[(rp[i] >> 16) & 127], 1);
    __syncthreads();

    // A2: exclusive scan over 128 counters (waves 0,1 fully active)
    int v = 0, inc = 0;
    if (tid < BINSZ) {
        v = cnt[tid];
        inc = v;
        #pragma unroll
        for (int d = 1; d < 64; d <<= 1) {
            int u = __shfl_up(inc, d);
            if ((tid & 63) >= d) inc += u;
        }
        if (tid == 63) sh_w0 = inc;
    }
    __syncthreads();
    if (tid < BINSZ) {
        int off = inc - v + (tid >= 64 ? sh_w0 : 0);
        offs[tid] = off;
        pos[tid] = off;
        if (tid == BINSZ - 1) offs[BINSZ] = off + v;
    }
    __syncthreads();

    // A3: scatter records into sorted LDS order
    for (int i = tid; i < n; i += 256) {
        unsigned r = rp[i];
        int p = atomicAdd(&pos[(r >> 16) & 127], 1);
        srec[p] = r;
    }
    __syncthreads();

    // B: per-node register accumulation; wave w owns lo = w, w+4, ...
    unsigned* ao = (unsigned*)aggb;
    const long nbase = (long)bin << 7;
    for (int lo = w; lo < BINSZ; lo += 4) {
        const int b = offs[lo], e = offs[lo + 1];
        float c0 = 0.f, c1 = 0.f;
        int i = b;
        for (; i + 8 <= e; i += 8) {
            unsigned r0_ = srec[i+0], r1_ = srec[i+1], r2_ = srec[i+2], r3_ = srec[i+3];
            unsigned r4_ = srec[i+4], r5_ = srec[i+5], r6_ = srec[i+6], r7_ = srec[i+7];
            unsigned q0 = xb2[(r0_ & 0xffffu) * 64 + l];
            unsigned q1 = xb2[(r1_ & 0xffffu) * 64 + l];
            unsigned q2 = xb2[(r2_ & 0xffffu) * 64 + l];
            unsigned q3 = xb2[(r3_ & 0xffffu) * 64 + l];
            unsigned q4 = xb2[(r4_ & 0xffffu) * 64 + l];
            unsigned q5 = xb2[(r5_ & 0xffffu) * 64 + l];
            unsigned q6 = xb2[(r6_ & 0xffffu) * 64 + l];
            unsigned q7 = xb2[(r7_ & 0xffffu) * 64 + l];
            c0 += bf_lo(q0); c1 += bf_hi(q0);
            c0 += bf_lo(q1); c1 += bf_hi(q1);
            c0 += bf_lo(q2); c1 += bf_hi(q2);
            c0 += bf_lo(q3); c1 += bf_hi(q3);
            c0 += bf_lo(q4); c1 += bf_hi(q4);
            c0 += bf_lo(q5); c1 += bf_hi(q5);
            c0 += bf_lo(q6); c1 += bf_hi(q6);
            c0 += bf_lo(q7); c1 += bf_hi(q7);
        }
        for (; i < e; ++i) {
            unsigned r = srec[i];
            unsigned q = xb2[(r & 0xffffu) * 64 + l];
            c0 += bf_lo(q); c1 += bf_hi(q);
        }
        ao[(nbase + lo) * 64 + l] = packbf(c0, c1);
    }
}

// ---------------- 3. MFMA MLP (unchanged, proven R3/R4/R5) ----------------
__global__ __launch_bounds__(256)
void mlp_mfma_kernel(const unsigned short* __restrict__ aggb, const unsigned short* __restrict__ xb,
                     const unsigned short* __restrict__ wb,
                     const float* __restrict__ brel, const float* __restrict__ blin,
                     float* __restrict__ out, float* __restrict__ sums, float* __restrict__ sumsq)
{
    __shared__ unsigned short smx2[32][136];

    const int tid = threadIdx.x;
    const int w = tid >> 6;
    const int l = tid & 63;
    const int l15 = l & 15;
    const int kg = l >> 4;
    const int n0 = blockIdx.x * 32;

    const unsigned short* Wrelb  = wb;
    const unsigned short* Wrootb = wb + 16384;
    const unsigned short* Wlinb  = wb + 32768;

    const int rA0 = n0 + l15, rA1 = n0 + 16 + l15;
    const long cA0 = min(rA0, NNODES - 1), cA1 = min(rA1, NNODES - 1);
    const int rB0 = w * 32 + l15, rB1 = rB0 + 16;

    f32x4 acc00 = {0.f,0.f,0.f,0.f}, acc01 = acc00, acc10 = acc00, acc11 = acc00;

    #pragma unroll
    for (int s = 0; s < 8; ++s) {
        const unsigned short* Ab = (s < 4) ? aggb : xb;
        const unsigned short* Bb = (s < 4) ? Wrelb : Wrootb;
        const int ko = (s & 3) * 32 + kg * 8;
        bf16x8 a0 = *(const bf16x8*)(Ab + cA0 * 128 + ko);
        bf16x8 a1 = *(const bf16x8*)(Ab + cA1 * 128 + ko);
        bf16x8 b0 = *(const bf16x8*)(Bb + rB0 * 128 + ko);
        bf16x8 b1 = *(const bf16x8*)(Bb + rB1 * 128 + ko);
        acc00 = __builtin_amdgcn_mfma_f32_16x16x32_bf16(a0, b0, acc00, 0, 0, 0);
        acc01 = __builtin_amdgcn_mfma_f32_16x16x32_bf16(a0, b1, acc01, 0, 0, 0);
        acc10 = __builtin_amdgcn_mfma_f32_16x16x32_bf16(a1, b0, acc10, 0, 0, 0);
        acc11 = __builtin_amdgcn_mfma_f32_16x16x32_bf16(a1, b1, acc11, 0, 0, 0);
    }

    {
        const float br0 = brel[rB0], br1 = brel[rB1];
        const int mr = kg * 4;
        #pragma unroll
        for (int r = 0; r < 4; ++r) {
            smx2[mr + r][rB0]      = (unsigned short)f2bf(lrelu(acc00[r] + br0));
            smx2[mr + r][rB1]      = (unsigned short)f2bf(lrelu(acc01[r] + br1));
            smx2[16 + mr + r][rB0] = (unsigned short)f2bf(lrelu(acc10[r] + br0));
            smx2[16 + mr + r][rB1] = (unsigned short)f2bf(lrelu(acc11[r] + br1));
        }
    }
    __syncthreads();

    f32x4 o00 = {0.f,0.f,0.f,0.f}, o01 = o00, o10 = o00, o11 = o00;
    #pragma unroll
    for (int s = 0; s < 4; ++s) {
        const int ko = s * 32 + kg * 8;
        bf16x8 a0 = *(const bf16x8*)(&smx2[l15][ko]);
        bf16x8 a1 = *(const bf16x8*)(&smx2[16 + l15][ko]);
        bf16x8 b0 = *(const bf16x8*)(Wlinb + rB0 * 128 + ko);
        bf16x8 b1 = *(const bf16x8*)(Wlinb + rB1 * 128 + ko);
        o00 = __builtin_amdgcn_mfma_f32_16x16x32_bf16(a0, b0, o00, 0, 0, 0);
        o01 = __builtin_amdgcn_mfma_f32_16x16x32_bf16(a0, b1, o01, 0, 0, 0);
        o10 = __builtin_amdgcn_mfma_f32_16x16x32_bf16(a1, b0, o10, 0, 0, 0);
        o11 = __builtin_amdgcn_mfma_f32_16x16x32_bf16(a1, b1, o11, 0, 0, 0);
    }

    const float bl0 = blin[rB0], bl1 = blin[rB1];
    float ps0 = 0.f, pq0 = 0.f, ps1 = 0.f, pq1 = 0.f;
    const int mr = kg * 4;
    #pragma unroll
    for (int mi = 0; mi < 2; ++mi) {
        f32x4 v0 = mi ? o10 : o00;
        f32x4 v1 = mi ? o11 : o01;
        #pragma unroll
        for (int r = 0; r < 4; ++r) {
            int m = n0 + mi * 16 + mr + r;
            if (m < NNODES) {
                float y0 = v0[r] + bl0;
                float y1 = v1[r] + bl1;
                out[(long)m * 128 + rB0] = y0;
                out[(long)m * 128 + rB1] = y1;
                ps0 += y0; pq0 += y0 * y0;
                ps1 += y1; pq1 += y1 * y1;
            }
        }
    }
    ps0 += __shfl_xor(ps0, 16); ps0 += __shfl_xor(ps0, 32);
    pq0 += __shfl_xor(pq0, 16); pq0 += __shfl_xor(pq0, 32);
    ps1 += __shfl_xor(ps1, 16); ps1 += __shfl_xor(ps1, 32);
    pq1 += __shfl_xor(pq1, 16); pq1 += __shfl_xor(pq1, 32);
    if (kg == 0) {
        atomicAdd(&sums[rB0], ps0);  atomicAdd(&sumsq[rB0], pq0);
        atomicAdd(&sums[rB1], ps1);  atomicAdd(&sumsq[rB1], pq1);
    }
}

// ---------------- 4. BN finalize ----------------
__global__ void bn_final_kernel(const float* __restrict__ sums, const float* __restrict__ sumsq,
                                const float* __restrict__ gamma, const float* __restrict__ beta,
                                float* __restrict__ ss)
{
    int h = threadIdx.x;
    float mean = sums[h] * (1.f / NNODES);
    float var = sumsq[h] * (1.f / NNODES) - mean * mean;
    float sc = gamma[h] * rsqrtf(var + BN_EPS);
    ss[h] = sc;
    ss[128 + h] = beta[h] - mean * sc;
}

// ---------------- 5. BN apply + leaky ----------------
__global__ __launch_bounds__(256)
void bn_apply_kernel(float* __restrict__ out, const float* __restrict__ ss)
{
    __shared__ float s_sc[128], s_sh[128];
    if (threadIdx.x < 128) {
        s_sc[threadIdx.x] = ss[threadIdx.x];
        s_sh[threadIdx.x] = ss[128 + threadIdx.x];
    }
    __syncthreads();
    const int total = NNODES * 32;
    float4* o4 = (float4*)out;
    for (int i = blockIdx.x * 256 + threadIdx.x; i < total; i += gridDim.x * 256) {
        float4 v = o4[i];
        int h = (i & 31) * 4;
        v.x = lrelu(v.x * s_sc[h + 0] + s_sh[h + 0]);
        v.y = lrelu(v.y * s_sc[h + 1] + s_sh[h + 1]);
        v.z = lrelu(v.z * s_sc[h + 2] + s_sh[h + 2]);
        v.w = lrelu(v.w * s_sc[h + 3] + s_sh[h + 3]);
        o4[i] = v;
    }
}

extern "C" void kernel_launch(void* const* d_in, const int* in_sizes, int n_in,
                              void* d_out, int out_size, void* d_ws, size_t ws_size,
                              hipStream_t stream)
{
    const float* x     = (const float*)d_in[0];
    const int*   ei    = (const int*)d_in[1];
    const float* Wrel  = (const float*)d_in[3];
    const float* brel  = (const float*)d_in[4];
    const float* Wroot = (const float*)d_in[5];
    const float* Wlin  = (const float*)d_in[6];
    const float* blin  = (const float*)d_in[7];
    const float* gamma = (const float*)d_in[8];
    const float* beta  = (const float*)d_in[9];
    float* out = (float*)d_out;

    const int n_edges = in_sizes[1] / 2;
    const int* src = ei;
    const int* dst = ei + n_edges;

    // workspace layout (bytes):
    // xb        @ 0          : 12,800,000   (x as bf16)
    // recs∪aggb @ 12,800,000 : 12,845,056   (NBINS*CAPG*4; aggb bf16 aliases linearly)
    // wb        @ 25,645,056 : 98,304
    // bcnt      @ 25,743,360 : 1,568        } memset together (3,616 B)
    // stats     @ 25,744,928 : 2,048        }
    char* ws = (char*)d_ws;
    unsigned short* xb   = (unsigned short*)ws;
    unsigned*       recs = (unsigned*)(ws + 12800000);
    unsigned short* aggb = (unsigned short*)(ws + 12800000);
    unsigned short* wb   = (unsigned short*)(ws + 25645056);
    int*   bcnt  = (int*)(ws + 25743360);
    float* sums  = (float*)(ws + 25744928);
    float* sumsq = sums + 128;
    float* ss    = sums + 256;

    hipMemsetAsync(bcnt, 0, 3616, stream);   // bcnt + stats

    prep_kernel<<<4096, 256, 0, stream>>>(x, Wrel, Wroot, Wlin, (unsigned*)xb, (unsigned*)wb);
    bin_kernel<<<PH1B, 256, 0, stream>>>(src, dst, bcnt, recs, n_edges);
    agg_kernel<<<NBINS, 256, 0, stream>>>((const unsigned*)xb, recs, bcnt, aggb);
    mlp_mfma_kernel<<<(NNODES + 31) / 32, 256, 0, stream>>>(
        aggb, xb, wb, brel, blin, out, sums, sumsq);
    bn_final_kernel<<<1, 128, 0, stream>>>(sums, sumsq, gamma, beta, ss);
    bn_apply_kernel<<<2048, 256, 0, stream>>>(out, ss);
}

// Round 7
// 194.499 us; speedup vs baseline: 8.5299x; 1.4903x over previous
//
#include <hip/hip_runtime.h>

#define NNODES 50000
#define NEG 0.01f
#define BN_EPS 1e-5f

#define BINSZ 64             // dst nodes per bin
#define NBINS 782            // ceil(50000/64)
#define CAPG 4096            // record capacity per bin (mean ~2046, max ~2350)
#define PH1B 256             // phase-1 blocks (1 per CU)
#define RING 32              // ring slots per bin (flush granule 16)

typedef __attribute__((ext_vector_type(8))) short bf16x8;
typedef __attribute__((ext_vector_type(4))) float f32x4;

__device__ __forceinline__ float lrelu(float v) { return v >= 0.f ? v : NEG * v; }
__device__ __forceinline__ float bf_lo(unsigned u) { return __uint_as_float(u << 16); }
__device__ __forceinline__ float bf_hi(unsigned u) { return __uint_as_float(u & 0xffff0000u); }
__device__ __forceinline__ unsigned f2bf(float x) {          // RNE
    unsigned u = __float_as_uint(x);
    return (u + 0x7fffu + ((u >> 16) & 1u)) >> 16;
}
__device__ __forceinline__ unsigned packbf(float lo, float hi) {
    unsigned b = __float_as_uint(hi);
    b = (b + 0x7fffu + ((b >> 16) & 1u)) & 0xffff0000u;
    return (f2bf(lo) & 0xffffu) | b;
}

// ---------------- 0. convert x + weights to bf16 ----------------
__global__ __launch_bounds__(256)
void prep_kernel(const float* __restrict__ x, const float* __restrict__ Wrel,
                 const float* __restrict__ Wroot, const float* __restrict__ Wlin,
                 unsigned* __restrict__ xb2, unsigned* __restrict__ wb2)
{
    const int NPX = 3200000;           // float pairs in x
    const int NPW = 24576;             // float pairs in 3 weight mats
    for (int i = blockIdx.x * 256 + threadIdx.x; i < NPX + NPW; i += gridDim.x * 256) {
        if (i < NPX) {
            float2 v = ((const float2*)x)[i];
            xb2[i] = packbf(v.x, v.y);
        } else {
            int j = i - NPX;
            const float* W = (j < 8192) ? Wrel : (j < 16384 ? Wroot : Wlin);
            float2 v = ((const float2*)W)[j & 8191];
            wb2[j] = packbf(v.x, v.y);
        }
    }
}

// ---------------- 1. multisplit: bin edges by dst>>6, line-combined flushes ----------------
// grid = 256 blocks = 1/CU, so the 106 KB LDS costs no occupancy.
__global__ __launch_bounds__(256)
void bin_kernel(const int* __restrict__ src, const int* __restrict__ dst,
                int* __restrict__ bcnt, unsigned* __restrict__ recs, int n_edges)
{
    __shared__ __align__(16) unsigned buf[NBINS][RING];   // 100 KB
    __shared__ int cnt[NBINS];
    __shared__ int flushed[NBINS];

    const int tid = threadIdx.x;
    for (int t = tid; t < NBINS; t += 256) { cnt[t] = 0; flushed[t] = 0; }
    __syncthreads();

    const int per = (n_edges + PH1B - 1) / PH1B;
    const int begin = blockIdx.x * per;
    const int end = min(begin + per, n_edges);

    for (int base = begin; base < end; base += 256) {
        int i = base + tid;
        if (i < end) {
            int s = src[i], d = dst[i];
            int b = d >> 6;
            unsigned rec = (unsigned)s | ((unsigned)(d & 63) << 16);
            int pos = atomicAdd(&cnt[b], 1);
            buf[b][pos & (RING - 1)] = rec;
        }
        __syncthreads();
        for (int t = tid; t < NBINS; t += 256) {
            int c = cnt[t];
            int f = flushed[t];
            while (c - f >= 16) {                    // 16 recs = 64B = 1 line
                int gbase = atomicAdd(&bcnt[t], 16);
                unsigned* dp = recs + (long)t * CAPG + gbase;
                int ro = f & (RING - 1);             // multiple of 16, no wrap
                #pragma unroll
                for (int k = 0; k < 4; ++k)
                    *(uint4*)(dp + k * 4) = *(uint4*)&buf[t][ro + k * 4];
                f += 16;
            }
            flushed[t] = f;
        }
        __syncthreads();
    }
    // drain leftovers (<16 per bin per block) — compact via reservation
    for (int t = tid; t < NBINS; t += 256) {
        int c = cnt[t], f = flushed[t];
        int n = c - f;
        if (n > 0) {
            int gbase = atomicAdd(&bcnt[t], n);
            unsigned* dp = recs + (long)t * CAPG + gbase;
            int ro = f & (RING - 1);
            for (int k = 0; k < n; ++k) dp[k] = buf[t][ro + k];
        }
    }
}

// ---------------- 2. per-bin: counting-sort records, register-accumulate ----------------
// One block per bin (782 blocks -> ~3 resident/CU). Phase A: int histogram
// (ds_add_u32) + single-wave 64-scan + scatter into sorted LDS. Phase B: waves
// walk contiguous per-node runs; lane l accumulates ch (2l,2l+1) in registers.
__global__ __launch_bounds__(256)
void agg_kernel(const unsigned* __restrict__ xb2, const unsigned* __restrict__ recs,
                const int* __restrict__ bcnt, unsigned short* __restrict__ aggb)
{
    __shared__ unsigned srec[CAPG];        // 16 KB sorted records
    __shared__ int cnt[BINSZ];
    __shared__ int pos[BINSZ];
    __shared__ int offs[BINSZ + 1];

    const int bin = blockIdx.x;
    const int tid = threadIdx.x;
    const int l = tid & 63, w = tid >> 6;

    if (tid < BINSZ) cnt[tid] = 0;
    __syncthreads();

    const int n = bcnt[bin];
    const unsigned* rp = recs + (long)bin * CAPG;

    // A1: histogram by local dst (native int ds atomics)
    for (int i = tid; i < n; i += 256)
        atomicAdd(&cnt[(rp[i] >> 16) & 63], 1);
    __syncthreads();

    // A2: exclusive scan over 64 counters (wave 0)
    if (tid < 64) {
        int v = cnt[tid];
        int inc = v;
        #pragma unroll
        for (int d = 1; d < 64; d <<= 1) {
            int u = __shfl_up(inc, d);
            if (tid >= d) inc += u;
        }
        offs[tid] = inc - v;
        pos[tid] = inc - v;
        if (tid == 63) offs[64] = inc;
    }
    __syncthreads();

    // A3: scatter records into sorted LDS order
    for (int i = tid; i < n; i += 256) {
        unsigned r = rp[i];
        int p = atomicAdd(&pos[(r >> 16) & 63], 1);
        srec[p] = r;
    }
    __syncthreads();

    // B: per-node register accumulation; wave w owns lo = w, w+4, ...
    unsigned* ao = (unsigned*)aggb;
    const long nbase = (long)bin << 6;
    for (int lo = w; lo < BINSZ; lo += 4) {
        const int b = offs[lo], e = offs[lo + 1];
        float c0 = 0.f, c1 = 0.f;
        int i = b;
        for (; i + 8 <= e; i += 8) {
            unsigned r0_ = srec[i+0], r1_ = srec[i+1], r2_ = srec[i+2], r3_ = srec[i+3];
            unsigned r4_ = srec[i+4], r5_ = srec[i+5], r6_ = srec[i+6], r7_ = srec[i+7];
            unsigned q0 = xb2[(r0_ & 0xffffu) * 64 + l];
            unsigned q1 = xb2[(r1_ & 0xffffu) * 64 + l];
            unsigned q2 = xb2[(r2_ & 0xffffu) * 64 + l];
            unsigned q3 = xb2[(r3_ & 0xffffu) * 64 + l];
            unsigned q4 = xb2[(r4_ & 0xffffu) * 64 + l];
            unsigned q5 = xb2[(r5_ & 0xffffu) * 64 + l];
            unsigned q6 = xb2[(r6_ & 0xffffu) * 64 + l];
            unsigned q7 = xb2[(r7_ & 0xffffu) * 64 + l];
            c0 += bf_lo(q0); c1 += bf_hi(q0);
            c0 += bf_lo(q1); c1 += bf_hi(q1);
            c0 += bf_lo(q2); c1 += bf_hi(q2);
            c0 += bf_lo(q3); c1 += bf_hi(q3);
            c0 += bf_lo(q4); c1 += bf_hi(q4);
            c0 += bf_lo(q5); c1 += bf_hi(q5);
            c0 += bf_lo(q6); c1 += bf_hi(q6);
            c0 += bf_lo(q7); c1 += bf_hi(q7);
        }
        for (; i < e; ++i) {
            unsigned r = srec[i];
            unsigned q = xb2[(r & 0xffffu) * 64 + l];
            c0 += bf_lo(q); c1 += bf_hi(q);
        }
        ao[(nbase + lo) * 64 + l] = packbf(c0, c1);
    }
}

// ---------------- 3. MFMA MLP (unchanged, proven R3-R6) ----------------
__global__ __launch_bounds__(256)
void mlp_mfma_kernel(const unsigned short* __restrict__ aggb, const unsigned short* __restrict__ xb,
                     const unsigned short* __restrict__ wb,
                     const float* __restrict__ brel, const float* __restrict__ blin,
                     float* __restrict__ out, float* __restrict__ sums, float* __restrict__ sumsq)
{
    __shared__ unsigned short smx2[32][136];

    const int tid = threadIdx.x;
    const int w = tid >> 6;
    const int l = tid & 63;
    const int l15 = l & 15;
    const int kg = l >> 4;
    const int n0 = blockIdx.x * 32;

    const unsigned short* Wrelb  = wb;
    const unsigned short* Wrootb = wb + 16384;
    const unsigned short* Wlinb  = wb + 32768;

    const int rA0 = n0 + l15, rA1 = n0 + 16 + l15;
    const long cA0 = min(rA0, NNODES - 1), cA1 = min(rA1, NNODES - 1);
    const int rB0 = w * 32 + l15, rB1 = rB0 + 16;

    f32x4 acc00 = {0.f,0.f,0.f,0.f}, acc01 = acc00, acc10 = acc00, acc11 = acc00;

    #pragma unroll
    for (int s = 0; s < 8; ++s) {
        const unsigned short* Ab = (s < 4) ? aggb : xb;
        const unsigned short* Bb = (s < 4) ? Wrelb : Wrootb;
        const int ko = (s & 3) * 32 + kg * 8;
        bf16x8 a0 = *(const bf16x8*)(Ab + cA0 * 128 + ko);
        bf16x8 a1 = *(const bf16x8*)(Ab + cA1 * 128 + ko);
        bf16x8 b0 = *(const bf16x8*)(Bb + rB0 * 128 + ko);
        bf16x8 b1 = *(const bf16x8*)(Bb + rB1 * 128 + ko);
        acc00 = __builtin_amdgcn_mfma_f32_16x16x32_bf16(a0, b0, acc00, 0, 0, 0);
        acc01 = __builtin_amdgcn_mfma_f32_16x16x32_bf16(a0, b1, acc01, 0, 0, 0);
        acc10 = __builtin_amdgcn_mfma_f32_16x16x32_bf16(a1, b0, acc10, 0, 0, 0);
        acc11 = __builtin_amdgcn_mfma_f32_16x16x32_bf16(a1, b1, acc11, 0, 0, 0);
    }

    {
        const float br0 = brel[rB0], br1 = brel[rB1];
        const int mr = kg * 4;
        #pragma unroll
        for (int r = 0; r < 4; ++r) {
            smx2[mr + r][rB0]      = (unsigned short)f2bf(lrelu(acc00[r] + br0));
            smx2[mr + r][rB1]      = (unsigned short)f2bf(lrelu(acc01[r] + br1));
            smx2[16 + mr + r][rB0] = (unsigned short)f2bf(lrelu(acc10[r] + br0));
            smx2[16 + mr + r][rB1] = (unsigned short)f2bf(lrelu(acc11[r] + br1));
        }
    }
    __syncthreads();

    f32x4 o00 = {0.f,0.f,0.f,0.f}, o01 = o00, o10 = o00, o11 = o00;
    #pragma unroll
    for (int s = 0; s < 4; ++s) {
        const int ko = s * 32 + kg * 8;
        bf16x8 a0 = *(const bf16x8*)(&smx2[l15][ko]);
        bf16x8 a1 = *(const bf16x8*)(&smx2[16 + l15][ko]);
        bf16x8 b0 = *(const bf16x8*)(Wlinb + rB0 * 128 + ko);
        bf16x8 b1 = *(const bf16x8*)(Wlinb + rB1 * 128 + ko);
        o00 = __builtin_amdgcn_mfma_f32_16x16x32_bf16(a0, b0, o00, 0, 0, 0);
        o01 = __builtin_amdgcn_mfma_f32_16x16x32_bf16(a0, b1, o01, 0, 0, 0);
        o10 = __builtin_amdgcn_mfma_f32_16x16x32_bf16(a1, b0, o10, 0, 0, 0);
        o11 = __builtin_amdgcn_mfma_f32_16x16x32_bf16(a1, b1, o11, 0, 0, 0);
    }

    const float bl0 = blin[rB0], bl1 = blin[rB1];
    float ps0 = 0.f, pq0 = 0.f, ps1 = 0.f, pq1 = 0.f;
    const int mr = kg * 4;
    #pragma unroll
    for (int mi = 0; mi < 2; ++mi) {
        f32x4 v0 = mi ? o10 : o00;
        f32x4 v1 = mi ? o11 : o01;
        #pragma unroll
        for (int r = 0; r < 4; ++r) {
            int m = n0 + mi * 16 + mr + r;
            if (m < NNODES) {
                float y0 = v0[r] + bl0;
                float y1 = v1[r] + bl1;
                out[(long)m * 128 + rB0] = y0;
                out[(long)m * 128 + rB1] = y1;
                ps0 += y0; pq0 += y0 * y0;
                ps1 += y1; pq1 += y1 * y1;
            }
        }
    }
    ps0 += __shfl_xor(ps0, 16); ps0 += __shfl_xor(ps0, 32);
    pq0 += __shfl_xor(pq0, 16); pq0 += __shfl_xor(pq0, 32);
    ps1 += __shfl_xor(ps1, 16); ps1 += __shfl_xor(ps1, 32);
    pq1 += __shfl_xor(pq1, 16); pq1 += __shfl_xor(pq1, 32);
    if (kg == 0) {
        atomicAdd(&sums[rB0], ps0);  atomicAdd(&sumsq[rB0], pq0);
        atomicAdd(&sums[rB1], ps1);  atomicAdd(&sumsq[rB1], pq1);
    }
}

// ---------------- 4. BN finalize ----------------
__global__ void bn_final_kernel(const float* __restrict__ sums, const float* __restrict__ sumsq,
                                const float* __restrict__ gamma, const float* __restrict__ beta,
                                float* __restrict__ ss)
{
    int h = threadIdx.x;
    float mean = sums[h] * (1.f / NNODES);
    float var = sumsq[h] * (1.f / NNODES) - mean * mean;
    float sc = gamma[h] * rsqrtf(var + BN_EPS);
    ss[h] = sc;
    ss[128 + h] = beta[h] - mean * sc;
}

// ---------------- 5. BN apply + leaky ----------------
__global__ __launch_bounds__(256)
void bn_apply_kernel(float* __restrict__ out, const float* __restrict__ ss)
{
    __shared__ float s_sc[128], s_sh[128];
    if (threadIdx.x < 128) {
        s_sc[threadIdx.x] = ss[threadIdx.x];
        s_sh[threadIdx.x] = ss[128 + threadIdx.x];
    }
    __syncthreads();
    const int total = NNODES * 32;
    float4* o4 = (float4*)out;
    for (int i = blockIdx.x * 256 + threadIdx.x; i < total; i += gridDim.x * 256) {
        float4 v = o4[i];
        int h = (i & 31) * 4;
        v.x = lrelu(v.x * s_sc[h + 0] + s_sh[h + 0]);
        v.y = lrelu(v.y * s_sc[h + 1] + s_sh[h + 1]);
        v.z = lrelu(v.z * s_sc[h + 2] + s_sh[h + 2]);
        v.w = lrelu(v.w * s_sc[h + 3] + s_sh[h + 3]);
        o4[i] = v;
    }
}

extern "C" void kernel_launch(void* const* d_in, const int* in_sizes, int n_in,
                              void* d_out, int out_size, void* d_ws, size_t ws_size,
                              hipStream_t stream)
{
    const float* x     = (const float*)d_in[0];
    const int*   ei    = (const int*)d_in[1];
    const float* Wrel  = (const float*)d_in[3];
    const float* brel  = (const float*)d_in[4];
    const float* Wroot = (const float*)d_in[5];
    const float* Wlin  = (const float*)d_in[6];
    const float* blin  = (const float*)d_in[7];
    const float* gamma = (const float*)d_in[8];
    const float* beta  = (const float*)d_in[9];
    float* out = (float*)d_out;

    const int n_edges = in_sizes[1] / 2;
    const int* src = ei;
    const int* dst = ei + n_edges;

    // workspace layout (bytes):
    // xb        @ 0          : 12,800,000   (x as bf16)
    // recs∪aggb @ 12,800,000 : 12,812,288   (NBINS*CAPG*4 = 50048 agg rows bf16, aliased)
    // wb        @ 25,612,288 : 98,304
    // bcnt      @ 25,710,592 : 3,128        } memset together (5,248 B)
    // stats     @ 25,713,792 : 2,048        }   -> total 25.72 MB
    char* ws = (char*)d_ws;
    unsigned short* xb   = (unsigned short*)ws;
    unsigned*       recs = (unsigned*)(ws + 12800000);
    unsigned short* aggb = (unsigned short*)(ws + 12800000);
    unsigned short* wb   = (unsigned short*)(ws + 25612288);
    int*   bcnt  = (int*)(ws + 25710592);
    float* sums  = (float*)(ws + 25713792);
    float* sumsq = sums + 128;
    float* ss    = sums + 256;

    hipMemsetAsync(bcnt, 0, 5248, stream);   // bcnt + stats

    prep_kernel<<<4096, 256, 0, stream>>>(x, Wrel, Wroot, Wlin, (unsigned*)xb, (unsigned*)wb);
    bin_kernel<<<PH1B, 256, 0, stream>>>(src, dst, bcnt, recs, n_edges);
    agg_kernel<<<NBINS, 256, 0, stream>>>((const unsigned*)xb, recs, bcnt, aggb);
    mlp_mfma_kernel<<<(NNODES + 31) / 32, 256, 0, stream>>>(
        aggb, xb, wb, brel, blin, out, sums, sumsq);
    bn_final_kernel<<<1, 128, 0, stream>>>(sums, sumsq, gamma, beta, ss);
    bn_apply_kernel<<<2048, 256, 0, stream>>>(out, ss);
}

// Round 8
// 173.753 us; speedup vs baseline: 9.5484x; 1.1194x over previous
//
#include <hip/hip_runtime.h>

#define NNODES 50000
#define NEG 0.01f
#define BN_EPS 1e-5f

#define BINSZ 64             // dst nodes per bin
#define NBINS 782            // ceil(50000/64)
#define CAPG 4096            // record capacity per bin (mean ~2046)
#define PH1B 256             // phase-1 blocks (1 per CU)
#define RING 32              // ring slots per bin (flush granule 16)

typedef __attribute__((ext_vector_type(8))) short bf16x8;
typedef __attribute__((ext_vector_type(4))) float f32x4;

__device__ __forceinline__ float lrelu(float v) { return v >= 0.f ? v : NEG * v; }
__device__ __forceinline__ float bf_lo(unsigned u) { return __uint_as_float(u << 16); }
__device__ __forceinline__ float bf_hi(unsigned u) { return __uint_as_float(u & 0xffff0000u); }
__device__ __forceinline__ unsigned f2bf(float x) {          // RNE
    unsigned u = __float_as_uint(x);
    return (u + 0x7fffu + ((u >> 16) & 1u)) >> 16;
}
__device__ __forceinline__ unsigned packbf(float lo, float hi) {
    unsigned b = __float_as_uint(hi);
    b = (b + 0x7fffu + ((b >> 16) & 1u)) & 0xffff0000u;
    return (f2bf(lo) & 0xffffu) | b;
}

// ---------------- 0. convert x + weights to bf16 ----------------
__global__ __launch_bounds__(256)
void prep_kernel(const float* __restrict__ x, const float* __restrict__ Wrel,
                 const float* __restrict__ Wroot, const float* __restrict__ Wlin,
                 unsigned* __restrict__ xb2, unsigned* __restrict__ wb2)
{
    const int NPX = 3200000;           // float pairs in x
    const int NPW = 24576;             // float pairs in 3 weight mats
    for (int i = blockIdx.x * 256 + threadIdx.x; i < NPX + NPW; i += gridDim.x * 256) {
        if (i < NPX) {
            float2 v = ((const float2*)x)[i];
            xb2[i] = packbf(v.x, v.y);
        } else {
            int j = i - NPX;
            const float* W = (j < 8192) ? Wrel : (j < 16384 ? Wroot : Wlin);
            float2 v = ((const float2*)W)[j & 8191];
            wb2[j] = packbf(v.x, v.y);
        }
    }
}

// ---------------- 1. multisplit: bin edges by dst>>6, line-combined flushes ----------------
__global__ __launch_bounds__(256)
void bin_kernel(const int* __restrict__ src, const int* __restrict__ dst,
                int* __restrict__ bcnt, unsigned* __restrict__ recs, int n_edges)
{
    __shared__ __align__(16) unsigned buf[NBINS][RING];   // 100 KB (grid=1/CU: free)
    __shared__ int cnt[NBINS];
    __shared__ int flushed[NBINS];

    const int tid = threadIdx.x;
    for (int t = tid; t < NBINS; t += 256) { cnt[t] = 0; flushed[t] = 0; }
    __syncthreads();

    const int per = (n_edges + PH1B - 1) / PH1B;
    const int begin = blockIdx.x * per;
    const int end = min(begin + per, n_edges);

    for (int base = begin; base < end; base += 256) {
        int i = base + tid;
        if (i < end) {
            int s = src[i], d = dst[i];
            int b = d >> 6;
            unsigned rec = (unsigned)s | ((unsigned)(d & 63) << 16);
            int pos = atomicAdd(&cnt[b], 1);
            buf[b][pos & (RING - 1)] = rec;
        }
        __syncthreads();
        for (int t = tid; t < NBINS; t += 256) {
            int c = cnt[t];
            int f = flushed[t];
            while (c - f >= 16) {                    // 16 recs = 64B = 1 line
                int gbase = atomicAdd(&bcnt[t], 16);
                unsigned* dp = recs + (long)t * CAPG + gbase;
                int ro = f & (RING - 1);             // multiple of 16, no wrap
                #pragma unroll
                for (int k = 0; k < 4; ++k)
                    *(uint4*)(dp + k * 4) = *(uint4*)&buf[t][ro + k * 4];
                f += 16;
            }
            flushed[t] = f;
        }
        __syncthreads();
    }
    for (int t = tid; t < NBINS; t += 256) {
        int c = cnt[t], f = flushed[t];
        int n = c - f;
        if (n > 0) {
            int gbase = atomicAdd(&bcnt[t], n);
            unsigned* dp = recs + (long)t * CAPG + gbase;
            int ro = f & (RING - 1);
            for (int k = 0; k < n; ++k) dp[k] = buf[t][ro + k];
        }
    }
}

// ---------------- 2. FUSED per-bin aggregate + MLP + BN partials ----------------
// One block per bin of 64 nodes. Phase A: counting-sort records in LDS,
// register-accumulate agg rows, deposit into pitch-136 LDS tile (bank-safe
// for b128 MFMA reads). Phase B: wave w computes nodes [w*16,w*16+16) x all
// 128 out channels: stage1 K=256 over [agg(LDS) | x(global)], lrelu -> x2
// back into same LDS rows (wave-private), stage2 K=128 -> out fp32.
// BN partials reduced in LDS (srec reused), 256 atomics per block.
__global__ __launch_bounds__(256, 4)
void agg_mlp_kernel(const unsigned* __restrict__ xb2, const unsigned* __restrict__ recs,
                    const int* __restrict__ bcnt, const unsigned short* __restrict__ wb,
                    const float* __restrict__ brel, const float* __restrict__ blin,
                    float* __restrict__ out, float* __restrict__ sums,
                    float* __restrict__ sumsq)
{
    __shared__ unsigned srec[CAPG];                       // 16 KB (later: BN scratch)
    __shared__ int cnt[BINSZ];
    __shared__ int pos[BINSZ];
    __shared__ int offs[BINSZ + 1];
    __shared__ __align__(16) unsigned short smA[BINSZ][136];  // 17.4 KB

    const int bin = blockIdx.x;
    const int tid = threadIdx.x;
    const int l = tid & 63, w = tid >> 6;
    const int l15 = l & 15, kg = l >> 4;

    if (tid < BINSZ) cnt[tid] = 0;
    __syncthreads();

    const int n = bcnt[bin];
    const unsigned* rp = recs + (long)bin * CAPG;

    // A1: histogram by local dst
    for (int i = tid; i < n; i += 256)
        atomicAdd(&cnt[(rp[i] >> 16) & 63], 1);
    __syncthreads();

    // A2: exclusive scan over 64 counters (wave 0)
    if (tid < 64) {
        int v = cnt[tid];
        int inc = v;
        #pragma unroll
        for (int d = 1; d < 64; d <<= 1) {
            int u = __shfl_up(inc, d);
            if (tid >= d) inc += u;
        }
        offs[tid] = inc - v;
        pos[tid] = inc - v;
        if (tid == 63) offs[64] = inc;
    }
    __syncthreads();

    // A3: scatter into sorted order
    for (int i = tid; i < n; i += 256) {
        unsigned r = rp[i];
        int p = atomicAdd(&pos[(r >> 16) & 63], 1);
        srec[p] = r;
    }
    __syncthreads();

    // A4: per-node register accumulation -> smA (lane l = ch pair 2l,2l+1)
    unsigned* smA32 = (unsigned*)smA;
    for (int lo = w; lo < BINSZ; lo += 4) {
        const int b = offs[lo], e = offs[lo + 1];
        float c0 = 0.f, c1 = 0.f;
        int i = b;
        for (; i + 8 <= e; i += 8) {
            unsigned r0_ = srec[i+0], r1_ = srec[i+1], r2_ = srec[i+2], r3_ = srec[i+3];
            unsigned r4_ = srec[i+4], r5_ = srec[i+5], r6_ = srec[i+6], r7_ = srec[i+7];
            unsigned q0 = xb2[(r0_ & 0xffffu) * 64 + l];
            unsigned q1 = xb2[(r1_ & 0xffffu) * 64 + l];
            unsigned q2 = xb2[(r2_ & 0xffffu) * 64 + l];
            unsigned q3 = xb2[(r3_ & 0xffffu) * 64 + l];
            unsigned q4 = xb2[(r4_ & 0xffffu) * 64 + l];
            unsigned q5 = xb2[(r5_ & 0xffffu) * 64 + l];
            unsigned q6 = xb2[(r6_ & 0xffffu) * 64 + l];
            unsigned q7 = xb2[(r7_ & 0xffffu) * 64 + l];
            c0 += bf_lo(q0); c1 += bf_hi(q0);
            c0 += bf_lo(q1); c1 += bf_hi(q1);
            c0 += bf_lo(q2); c1 += bf_hi(q2);
            c0 += bf_lo(q3); c1 += bf_hi(q3);
            c0 += bf_lo(q4); c1 += bf_hi(q4);
            c0 += bf_lo(q5); c1 += bf_hi(q5);
            c0 += bf_lo(q6); c1 += bf_hi(q6);
            c0 += bf_lo(q7); c1 += bf_hi(q7);
        }
        for (; i < e; ++i) {
            unsigned r = srec[i];
            unsigned q = xb2[(r & 0xffffu) * 64 + l];
            c0 += bf_lo(q); c1 += bf_hi(q);
        }
        smA32[lo * 68 + l] = packbf(c0, c1);   // pitch 68 uints = 136 ch
    }
    __syncthreads();   // smA ready; srec reads complete (free for reuse)

    // ---- Phase B: MLP ----
    const unsigned short* Wrelb  = wb;
    const unsigned short* Wrootb = wb + 16384;
    const unsigned short* Wlinb  = wb + 32768;
    const unsigned short* xbs = (const unsigned short*)xb2;

    const int row = w * 16 + l15;                        // A-frag node row (local)
    const int gA = bin * 64 + row;
    const long gAc = min(gA, NNODES - 1);

    f32x4 acc[8];
    #pragma unroll
    for (int nt = 0; nt < 8; ++nt) acc[nt] = (f32x4){0.f, 0.f, 0.f, 0.f};

    #pragma unroll
    for (int s = 0; s < 8; ++s) {
        const int ko = (s & 3) * 32 + kg * 8;
        bf16x8 a;
        if (s < 4) a = *(const bf16x8*)&smA[row][ko];
        else       a = *(const bf16x8*)(xbs + gAc * 128 + ko);
        const unsigned short* Bb = (s < 4) ? Wrelb : Wrootb;
        #pragma unroll
        for (int nt = 0; nt < 8; ++nt) {
            bf16x8 b = *(const bf16x8*)(Bb + (nt * 16 + l15) * 128 + ko);
            acc[nt] = __builtin_amdgcn_mfma_f32_16x16x32_bf16(a, b, acc[nt], 0, 0, 0);
        }
    }

    // x2 = lrelu(acc + brel) -> smA rows (wave-private: rows w*16..w*16+15)
    #pragma unroll
    for (int nt = 0; nt < 8; ++nt) {
        const float br = brel[nt * 16 + l15];
        #pragma unroll
        for (int r = 0; r < 4; ++r) {
            smA[w * 16 + kg * 4 + r][nt * 16 + l15] =
                (unsigned short)f2bf(lrelu(acc[nt][r] + br));
        }
    }
    __syncthreads();

    f32x4 acc2[8];
    #pragma unroll
    for (int nt = 0; nt < 8; ++nt) acc2[nt] = (f32x4){0.f, 0.f, 0.f, 0.f};

    #pragma unroll
    for (int s = 0; s < 4; ++s) {
        const int ko = s * 32 + kg * 8;
        bf16x8 a = *(const bf16x8*)&smA[row][ko];
        #pragma unroll
        for (int nt = 0; nt < 8; ++nt) {
            bf16x8 b = *(const bf16x8*)(Wlinb + (nt * 16 + l15) * 128 + ko);
            acc2[nt] = __builtin_amdgcn_mfma_f32_16x16x32_bf16(a, b, acc2[nt], 0, 0, 0);
        }
    }

    // epilogue: +blin, store fp32, BN partials via LDS (srec as scratch)
    float* redS = (float*)srec;   // [2][4][128]
    #pragma unroll
    for (int nt = 0; nt < 8; ++nt) {
        const int col = nt * 16 + l15;
        const float bl = blin[col];
        float ps = 0.f, pq = 0.f;
        #pragma unroll
        for (int r = 0; r < 4; ++r) {
            int g = bin * 64 + w * 16 + kg * 4 + r;
            if (g < NNODES) {
                float y = acc2[nt][r] + bl;
                out[(long)g * 128 + col] = y;
                ps += y; pq += y * y;
            }
        }
        ps += __shfl_xor(ps, 16); ps += __shfl_xor(ps, 32);
        pq += __shfl_xor(pq, 16); pq += __shfl_xor(pq, 32);
        if (kg == 0) {
            redS[(0 * 4 + w) * 128 + col] = ps;
            redS[(1 * 4 + w) * 128 + col] = pq;
        }
    }
    __syncthreads();
    if (tid < 128) {
        float s = redS[0 * 128 + tid] + redS[1 * 128 + tid]
                + redS[2 * 128 + tid] + redS[3 * 128 + tid];
        float q = redS[4 * 128 + tid] + redS[5 * 128 + tid]
                + redS[6 * 128 + tid] + redS[7 * 128 + tid];
        atomicAdd(&sums[tid], s);
        atomicAdd(&sumsq[tid], q);
    }
}

// ---------------- 3. BN finalize ----------------
__global__ void bn_final_kernel(const float* __restrict__ sums, const float* __restrict__ sumsq,
                                const float* __restrict__ gamma, const float* __restrict__ beta,
                                float* __restrict__ ss)
{
    int h = threadIdx.x;
    float mean = sums[h] * (1.f / NNODES);
    float var = sumsq[h] * (1.f / NNODES) - mean * mean;
    float sc = gamma[h] * rsqrtf(var + BN_EPS);
    ss[h] = sc;
    ss[128 + h] = beta[h] - mean * sc;
}

// ---------------- 4. BN apply + leaky (in-place fp32) ----------------
__global__ __launch_bounds__(256)
void bn_apply_kernel(float* __restrict__ out, const float* __restrict__ ss)
{
    __shared__ float s_sc[128], s_sh[128];
    if (threadIdx.x < 128) {
        s_sc[threadIdx.x] = ss[threadIdx.x];
        s_sh[threadIdx.x] = ss[128 + threadIdx.x];
    }
    __syncthreads();
    const int total = NNODES * 32;
    float4* o4 = (float4*)out;
    for (int i = blockIdx.x * 256 + threadIdx.x; i < total; i += gridDim.x * 256) {
        float4 v = o4[i];
        int h = (i & 31) * 4;
        v.x = lrelu(v.x * s_sc[h + 0] + s_sh[h + 0]);
        v.y = lrelu(v.y * s_sc[h + 1] + s_sh[h + 1]);
        v.z = lrelu(v.z * s_sc[h + 2] + s_sh[h + 2]);
        v.w = lrelu(v.w * s_sc[h + 3] + s_sh[h + 3]);
        o4[i] = v;
    }
}

extern "C" void kernel_launch(void* const* d_in, const int* in_sizes, int n_in,
                              void* d_out, int out_size, void* d_ws, size_t ws_size,
                              hipStream_t stream)
{
    const float* x     = (const float*)d_in[0];
    const int*   ei    = (const int*)d_in[1];
    const float* Wrel  = (const float*)d_in[3];
    const float* brel  = (const float*)d_in[4];
    const float* Wroot = (const float*)d_in[5];
    const float* Wlin  = (const float*)d_in[6];
    const float* blin  = (const float*)d_in[7];
    const float* gamma = (const float*)d_in[8];
    const float* beta  = (const float*)d_in[9];
    float* out = (float*)d_out;

    const int n_edges = in_sizes[1] / 2;
    const int* src = ei;
    const int* dst = ei + n_edges;

    // workspace layout (bytes):
    // xb    @ 0          : 12,800,000   (x as bf16)
    // recs  @ 12,800,000 : 12,812,288   (NBINS*CAPG*4)
    // wb    @ 25,612,288 : 98,304
    // bcnt  @ 25,710,592 : 3,128        } memset together (5,248 B)
    // stats @ 25,713,792 : 2,048        }   -> total 25.72 MB
    char* ws = (char*)d_ws;
    unsigned short* xb   = (unsigned short*)ws;
    unsigned*       recs = (unsigned*)(ws + 12800000);
    unsigned short* wb   = (unsigned short*)(ws + 25612288);
    int*   bcnt  = (int*)(ws + 25710592);
    float* sums  = (float*)(ws + 25713792);
    float* sumsq = sums + 128;
    float* ss    = sums + 256;

    hipMemsetAsync(bcnt, 0, 5248, stream);   // bcnt + stats

    prep_kernel<<<4096, 256, 0, stream>>>(x, Wrel, Wroot, Wlin, (unsigned*)xb, (unsigned*)wb);
    bin_kernel<<<PH1B, 256, 0, stream>>>(src, dst, bcnt, recs, n_edges);
    agg_mlp_kernel<<<NBINS, 256, 0, stream>>>((const unsigned*)xb, recs, bcnt, wb,
                                              brel, blin, out, sums, sumsq);
    bn_final_kernel<<<1, 128, 0, stream>>>(sums, sumsq, gamma, beta, ss);
    bn_apply_kernel<<<2048, 256, 0, stream>>>(out, ss);
}

// Round 9
// 164.481 us; speedup vs baseline: 10.0867x; 1.0564x over previous
//
#include <hip/hip_runtime.h>

#define NNODES 50000
#define NEG 0.01f
#define BN_EPS 1e-5f

#define BINSZ 64             // dst nodes per bin
#define NBINS 782            // ceil(50000/64)
#define CAPG 4096            // record capacity per bin (mean ~2046)
#define PH1B 256             // phase-1 blocks (1 per CU)
#define RING 32              // ring slots per bin (flush granule 16)

typedef __attribute__((ext_vector_type(8))) short bf16x8;
typedef __attribute__((ext_vector_type(4))) float f32x4;

__device__ __forceinline__ float lrelu(float v) { return v >= 0.f ? v : NEG * v; }
__device__ __forceinline__ float bf_lo(unsigned u) { return __uint_as_float(u << 16); }
__device__ __forceinline__ float bf_hi(unsigned u) { return __uint_as_float(u & 0xffff0000u); }
__device__ __forceinline__ unsigned f2bf(float x) {          // RNE
    unsigned u = __float_as_uint(x);
    return (u + 0x7fffu + ((u >> 16) & 1u)) >> 16;
}
__device__ __forceinline__ unsigned packbf(float lo, float hi) {
    unsigned b = __float_as_uint(hi);
    b = (b + 0x7fffu + ((b >> 16) & 1u)) & 0xffff0000u;
    return (f2bf(lo) & 0xffffu) | b;
}
__device__ __forceinline__ void acc8(float* c, uint4 q) {
    c[0] += bf_lo(q.x); c[1] += bf_hi(q.x);
    c[2] += bf_lo(q.y); c[3] += bf_hi(q.y);
    c[4] += bf_lo(q.z); c[5] += bf_hi(q.z);
    c[6] += bf_lo(q.w); c[7] += bf_hi(q.w);
}

// ---------------- 0. convert x + weights to bf16 ----------------
__global__ __launch_bounds__(256)
void prep_kernel(const float* __restrict__ x, const float* __restrict__ Wrel,
                 const float* __restrict__ Wroot, const float* __restrict__ Wlin,
                 unsigned* __restrict__ xb2, unsigned* __restrict__ wb2)
{
    const int NPX = 3200000;           // float pairs in x
    const int NPW = 24576;             // float pairs in 3 weight mats
    for (int i = blockIdx.x * 256 + threadIdx.x; i < NPX + NPW; i += gridDim.x * 256) {
        if (i < NPX) {
            float2 v = ((const float2*)x)[i];
            xb2[i] = packbf(v.x, v.y);
        } else {
            int j = i - NPX;
            const float* W = (j < 8192) ? Wrel : (j < 16384 ? Wroot : Wlin);
            float2 v = ((const float2*)W)[j & 8191];
            wb2[j] = packbf(v.x, v.y);
        }
    }
}

// ---------------- 1. multisplit: bin edges by dst>>6, line-combined flushes ----------------
__global__ __launch_bounds__(256)
void bin_kernel(const int* __restrict__ src, const int* __restrict__ dst,
                int* __restrict__ bcnt, unsigned* __restrict__ recs, int n_edges)
{
    __shared__ __align__(16) unsigned buf[NBINS][RING];   // 100 KB (grid=1/CU: free)
    __shared__ int cnt[NBINS];
    __shared__ int flushed[NBINS];

    const int tid = threadIdx.x;
    for (int t = tid; t < NBINS; t += 256) { cnt[t] = 0; flushed[t] = 0; }
    __syncthreads();

    const int per = (n_edges + PH1B - 1) / PH1B;
    const int begin = blockIdx.x * per;
    const int end = min(begin + per, n_edges);

    for (int base = begin; base < end; base += 256) {
        int i = base + tid;
        if (i < end) {
            int s = src[i], d = dst[i];
            int b = d >> 6;
            unsigned rec = (unsigned)s | ((unsigned)(d & 63) << 16);
            int pos = atomicAdd(&cnt[b], 1);
            buf[b][pos & (RING - 1)] = rec;
        }
        __syncthreads();
        for (int t = tid; t < NBINS; t += 256) {
            int c = cnt[t];
            int f = flushed[t];
            while (c - f >= 16) {                    // 16 recs = 64B = 1 line
                int gbase = atomicAdd(&bcnt[t], 16);
                unsigned* dp = recs + (long)t * CAPG + gbase;
                int ro = f & (RING - 1);             // multiple of 16, no wrap
                #pragma unroll
                for (int k = 0; k < 4; ++k)
                    *(uint4*)(dp + k * 4) = *(uint4*)&buf[t][ro + k * 4];
                f += 16;
            }
            flushed[t] = f;
        }
        __syncthreads();
    }
    for (int t = tid; t < NBINS; t += 256) {
        int c = cnt[t], f = flushed[t];
        int n = c - f;
        if (n > 0) {
            int gbase = atomicAdd(&bcnt[t], n);
            unsigned* dp = recs + (long)t * CAPG + gbase;
            int ro = f & (RING - 1);
            for (int k = 0; k < n; ++k) dp[k] = buf[t][ro + k];
        }
    }
}

// ---------------- 2. FUSED per-bin aggregate + MLP + BN partials ----------------
// Gather phase: lane = (slot g16 = l>>4, chunk c16 = l&15). One uint4 load
// fetches 4 records (1 KB/wave-instruction); 16-record unroll = 4 KB in
// flight/wave. Run-end: shfl_xor(16/32) folds the 4 slots; lanes 0-15 write
// the smA row (pitch 136 shorts, 16B-aligned rows).
__global__ __launch_bounds__(256, 4)
void agg_mlp_kernel(const unsigned* __restrict__ xb2, const unsigned* __restrict__ recs,
                    const int* __restrict__ bcnt, const unsigned short* __restrict__ wb,
                    const float* __restrict__ brel, const float* __restrict__ blin,
                    float* __restrict__ out, float* __restrict__ sums,
                    float* __restrict__ sumsq)
{
    __shared__ unsigned srec[CAPG];                       // 16 KB (later: BN scratch)
    __shared__ int cnt[BINSZ];
    __shared__ int pos[BINSZ];
    __shared__ int offs[BINSZ + 1];
    __shared__ __align__(16) unsigned short smA[BINSZ][136];  // 17.4 KB

    const int bin = blockIdx.x;
    const int tid = threadIdx.x;
    const int l = tid & 63, w = tid >> 6;
    const int l15 = l & 15, kg = l >> 4;
    const int g16 = l >> 4, c16 = l & 15;    // gather: record slot / row chunk

    if (tid < BINSZ) cnt[tid] = 0;
    __syncthreads();

    const int n = bcnt[bin];
    const unsigned* rp = recs + (long)bin * CAPG;

    // A1: histogram by local dst
    for (int i = tid; i < n; i += 256)
        atomicAdd(&cnt[(rp[i] >> 16) & 63], 1);
    __syncthreads();

    // A2: exclusive scan over 64 counters (wave 0)
    if (tid < 64) {
        int v = cnt[tid];
        int inc = v;
        #pragma unroll
        for (int d = 1; d < 64; d <<= 1) {
            int u = __shfl_up(inc, d);
            if (tid >= d) inc += u;
        }
        offs[tid] = inc - v;
        pos[tid] = inc - v;
        if (tid == 63) offs[64] = inc;
    }
    __syncthreads();

    // A3: scatter into sorted order
    for (int i = tid; i < n; i += 256) {
        unsigned r = rp[i];
        int p = atomicAdd(&pos[(r >> 16) & 63], 1);
        srec[p] = r;
    }
    __syncthreads();

    // A4: per-node register accumulation, uint4 gather (4 records/load)
    unsigned* smA32 = (unsigned*)smA;
    for (int lo = w; lo < BINSZ; lo += 4) {
        const int b = offs[lo], e = offs[lo + 1];
        float c[8];
        #pragma unroll
        for (int k = 0; k < 8; ++k) c[k] = 0.f;

        int i = b;
        for (; i + 16 <= e; i += 16) {
            unsigned r0 = srec[i + g16];
            unsigned r1 = srec[i + 4 + g16];
            unsigned r2 = srec[i + 8 + g16];
            unsigned r3 = srec[i + 12 + g16];
            uint4 q0 = *((const uint4*)(xb2 + (r0 & 0xffffu) * 64) + c16);
            uint4 q1 = *((const uint4*)(xb2 + (r1 & 0xffffu) * 64) + c16);
            uint4 q2 = *((const uint4*)(xb2 + (r2 & 0xffffu) * 64) + c16);
            uint4 q3 = *((const uint4*)(xb2 + (r3 & 0xffffu) * 64) + c16);
            acc8(c, q0); acc8(c, q1); acc8(c, q2); acc8(c, q3);
        }
        for (; i + 4 <= e; i += 4) {
            unsigned r = srec[i + g16];
            uint4 q = *((const uint4*)(xb2 + (r & 0xffffu) * 64) + c16);
            acc8(c, q);
        }
        if (i < e) {                                   // 1..3 leftover records
            int idx = i + g16;
            unsigned r = srec[idx < e ? idx : e - 1];
            if (idx < e) {
                uint4 q = *((const uint4*)(xb2 + (r & 0xffffu) * 64) + c16);
                acc8(c, q);
            }
        }
        // fold the 4 record slots
        #pragma unroll
        for (int k = 0; k < 8; ++k) {
            c[k] += __shfl_xor(c[k], 16);
            c[k] += __shfl_xor(c[k], 32);
        }
        if (l < 16) {
            uint4 o;
            o.x = packbf(c[0], c[1]); o.y = packbf(c[2], c[3]);
            o.z = packbf(c[4], c[5]); o.w = packbf(c[6], c[7]);
            *((uint4*)(smA32 + lo * 68) + c16) = o;
        }
    }
    __syncthreads();   // smA ready; srec reads complete (free for reuse)

    // ---- Phase B: MLP ----
    const unsigned short* Wrelb  = wb;
    const unsigned short* Wrootb = wb + 16384;
    const unsigned short* Wlinb  = wb + 32768;
    const unsigned short* xbs = (const unsigned short*)xb2;

    const int row = w * 16 + l15;                        // A-frag node row (local)
    const int gA = bin * 64 + row;
    const long gAc = min(gA, NNODES - 1);

    f32x4 acc[8];
    #pragma unroll
    for (int nt = 0; nt < 8; ++nt) acc[nt] = (f32x4){0.f, 0.f, 0.f, 0.f};

    #pragma unroll
    for (int s = 0; s < 8; ++s) {
        const int ko = (s & 3) * 32 + kg * 8;
        bf16x8 a;
        if (s < 4) a = *(const bf16x8*)&smA[row][ko];
        else       a = *(const bf16x8*)(xbs + gAc * 128 + ko);
        const unsigned short* Bb = (s < 4) ? Wrelb : Wrootb;
        #pragma unroll
        for (int nt = 0; nt < 8; ++nt) {
            bf16x8 b = *(const bf16x8*)(Bb + (nt * 16 + l15) * 128 + ko);
            acc[nt] = __builtin_amdgcn_mfma_f32_16x16x32_bf16(a, b, acc[nt], 0, 0, 0);
        }
    }

    // x2 = lrelu(acc + brel) -> smA rows (wave-private: rows w*16..w*16+15)
    #pragma unroll
    for (int nt = 0; nt < 8; ++nt) {
        const float br = brel[nt * 16 + l15];
        #pragma unroll
        for (int r = 0; r < 4; ++r) {
            smA[w * 16 + kg * 4 + r][nt * 16 + l15] =
                (unsigned short)f2bf(lrelu(acc[nt][r] + br));
        }
    }
    __syncthreads();

    f32x4 acc2[8];
    #pragma unroll
    for (int nt = 0; nt < 8; ++nt) acc2[nt] = (f32x4){0.f, 0.f, 0.f, 0.f};

    #pragma unroll
    for (int s = 0; s < 4; ++s) {
        const int ko = s * 32 + kg * 8;
        bf16x8 a = *(const bf16x8*)&smA[row][ko];
        #pragma unroll
        for (int nt = 0; nt < 8; ++nt) {
            bf16x8 b = *(const bf16x8*)(Wlinb + (nt * 16 + l15) * 128 + ko);
            acc2[nt] = __builtin_amdgcn_mfma_f32_16x16x32_bf16(a, b, acc2[nt], 0, 0, 0);
        }
    }

    // epilogue: +blin, store fp32, BN partials via LDS (srec as scratch)
    float* redS = (float*)srec;   // [2][4][128]
    #pragma unroll
    for (int nt = 0; nt < 8; ++nt) {
        const int col = nt * 16 + l15;
        const float bl = blin[col];
        float ps = 0.f, pq = 0.f;
        #pragma unroll
        for (int r = 0; r < 4; ++r) {
            int g = bin * 64 + w * 16 + kg * 4 + r;
            if (g < NNODES) {
                float y = acc2[nt][r] + bl;
                out[(long)g * 128 + col] = y;
                ps += y; pq += y * y;
            }
        }
        ps += __shfl_xor(ps, 16); ps += __shfl_xor(ps, 32);
        pq += __shfl_xor(pq, 16); pq += __shfl_xor(pq, 32);
        if (kg == 0) {
            redS[(0 * 4 + w) * 128 + col] = ps;
            redS[(1 * 4 + w) * 128 + col] = pq;
        }
    }
    __syncthreads();
    if (tid < 128) {
        float s = redS[0 * 128 + tid] + redS[1 * 128 + tid]
                + redS[2 * 128 + tid] + redS[3 * 128 + tid];
        float q = redS[4 * 128 + tid] + redS[5 * 128 + tid]
                + redS[6 * 128 + tid] + redS[7 * 128 + tid];
        atomicAdd(&sums[tid], s);
        atomicAdd(&sumsq[tid], q);
    }
}

// ---------------- 3. BN finalize ----------------
__global__ void bn_final_kernel(const float* __restrict__ sums, const float* __restrict__ sumsq,
                                const float* __restrict__ gamma, const float* __restrict__ beta,
                                float* __restrict__ ss)
{
    int h = threadIdx.x;
    float mean = sums[h] * (1.f / NNODES);
    float var = sumsq[h] * (1.f / NNODES) - mean * mean;
    float sc = gamma[h] * rsqrtf(var + BN_EPS);
    ss[h] = sc;
    ss[128 + h] = beta[h] - mean * sc;
}

// ---------------- 4. BN apply + leaky (in-place fp32) ----------------
__global__ __launch_bounds__(256)
void bn_apply_kernel(float* __restrict__ out, const float* __restrict__ ss)
{
    __shared__ float s_sc[128], s_sh[128];
    if (threadIdx.x < 128) {
        s_sc[threadIdx.x] = ss[threadIdx.x];
        s_sh[threadIdx.x] = ss[128 + threadIdx.x];
    }
    __syncthreads();
    const int total = NNODES * 32;
    float4* o4 = (float4*)out;
    for (int i = blockIdx.x * 256 + threadIdx.x; i < total; i += gridDim.x * 256) {
        float4 v = o4[i];
        int h = (i & 31) * 4;
        v.x = lrelu(v.x * s_sc[h + 0] + s_sh[h + 0]);
        v.y = lrelu(v.y * s_sc[h + 1] + s_sh[h + 1]);
        v.z = lrelu(v.z * s_sc[h + 2] + s_sh[h + 2]);
        v.w = lrelu(v.w * s_sc[h + 3] + s_sh[h + 3]);
        o4[i] = v;
    }
}

extern "C" void kernel_launch(void* const* d_in, const int* in_sizes, int n_in,
                              void* d_out, int out_size, void* d_ws, size_t ws_size,
                              hipStream_t stream)
{
    const float* x     = (const float*)d_in[0];
    const int*   ei    = (const int*)d_in[1];
    const float* Wrel  = (const float*)d_in[3];
    const float* brel  = (const float*)d_in[4];
    const float* Wroot = (const float*)d_in[5];
    const float* Wlin  = (const float*)d_in[6];
    const float* blin  = (const float*)d_in[7];
    const float* gamma = (const float*)d_in[8];
    const float* beta  = (const float*)d_in[9];
    float* out = (float*)d_out;

    const int n_edges = in_sizes[1] / 2;
    const int* src = ei;
    const int* dst = ei + n_edges;

    // workspace layout (bytes):
    // xb    @ 0          : 12,800,000   (x as bf16)
    // recs  @ 12,800,000 : 12,812,288   (NBINS*CAPG*4)
    // wb    @ 25,612,288 : 98,304
    // bcnt  @ 25,710,592 : 3,128        } memset together (5,248 B)
    // stats @ 25,713,792 : 2,048        }   -> total 25.72 MB
    char* ws = (char*)d_ws;
    unsigned short* xb   = (unsigned short*)ws;
    unsigned*       recs = (unsigned*)(ws + 12800000);
    unsigned short* wb   = (unsigned short*)(ws + 25612288);
    int*   bcnt  = (int*)(ws + 25710592);
    float* sums  = (float*)(ws + 25713792);
    float* sumsq = sums + 128;
    float* ss    = sums + 256;

    hipMemsetAsync(bcnt, 0, 5248, stream);   // bcnt + stats

    prep_kernel<<<4096, 256, 0, stream>>>(x, Wrel, Wroot, Wlin, (unsigned*)xb, (unsigned*)wb);
    bin_kernel<<<PH1B, 256, 0, stream>>>(src, dst, bcnt, recs, n_edges);
    agg_mlp_kernel<<<NBINS, 256, 0, stream>>>((const unsigned*)xb, recs, bcnt, wb,
                                              brel, blin, out, sums, sumsq);
    bn_final_kernel<<<1, 128, 0, stream>>>(sums, sumsq, gamma, beta, ss);
    bn_apply_kernel<<<2048, 256, 0, stream>>>(out, ss);
}

// Round 10
// 164.114 us; speedup vs baseline: 10.1092x; 1.0022x over previous
//
#include <hip/hip_runtime.h>

#define NNODES 50000
#define NEG 0.01f
#define BN_EPS 1e-5f

#define BINSZ 64             // dst nodes per bin
#define NBINS 782            // ceil(50000/64)
#define CAPG 4096            // record capacity per bin (mean ~2046)
#define PH1B 256             // phase-1 blocks (1 per CU)
#define RING 32              // ring slots per bin (flush granule 16)

typedef __attribute__((ext_vector_type(8))) short bf16x8;
typedef __attribute__((ext_vector_type(4))) float f32x4;

__device__ __forceinline__ float lrelu(float v) { return v >= 0.f ? v : NEG * v; }
__device__ __forceinline__ float bf_lo(unsigned u) { return __uint_as_float(u << 16); }
__device__ __forceinline__ float bf_hi(unsigned u) { return __uint_as_float(u & 0xffff0000u); }
__device__ __forceinline__ unsigned f2bf(float x) {          // RNE
    unsigned u = __float_as_uint(x);
    return (u + 0x7fffu + ((u >> 16) & 1u)) >> 16;
}
__device__ __forceinline__ unsigned packbf(float lo, float hi) {
    unsigned b = __float_as_uint(hi);
    b = (b + 0x7fffu + ((b >> 16) & 1u)) & 0xffff0000u;
    return (f2bf(lo) & 0xffffu) | b;
}
__device__ __forceinline__ void acc8(float* c, uint4 q) {
    c[0] += bf_lo(q.x); c[1] += bf_hi(q.x);
    c[2] += bf_lo(q.y); c[3] += bf_hi(q.y);
    c[4] += bf_lo(q.z); c[5] += bf_hi(q.z);
    c[6] += bf_lo(q.w); c[7] += bf_hi(q.w);
}

// ---------------- 0. convert x + weights to bf16 ----------------
__global__ __launch_bounds__(256)
void prep_kernel(const float* __restrict__ x, const float* __restrict__ Wrel,
                 const float* __restrict__ Wroot, const float* __restrict__ Wlin,
                 unsigned* __restrict__ xb2, unsigned* __restrict__ wb2)
{
    const int NPX = 3200000;           // float pairs in x
    const int NPW = 24576;             // float pairs in 3 weight mats
    for (int i = blockIdx.x * 256 + threadIdx.x; i < NPX + NPW; i += gridDim.x * 256) {
        if (i < NPX) {
            float2 v = ((const float2*)x)[i];
            xb2[i] = packbf(v.x, v.y);
        } else {
            int j = i - NPX;
            const float* W = (j < 8192) ? Wrel : (j < 16384 ? Wroot : Wlin);
            float2 v = ((const float2*)W)[j & 8191];
            wb2[j] = packbf(v.x, v.y);
        }
    }
}

// ---------------- 1. multisplit: bin edges by dst>>6, line-combined flushes ----------------
__global__ __launch_bounds__(256)
void bin_kernel(const int* __restrict__ src, const int* __restrict__ dst,
                int* __restrict__ bcnt, unsigned* __restrict__ recs, int n_edges)
{
    __shared__ __align__(16) unsigned buf[NBINS][RING];   // 100 KB (grid=1/CU: free)
    __shared__ int cnt[NBINS];
    __shared__ int flushed[NBINS];

    const int tid = threadIdx.x;
    for (int t = tid; t < NBINS; t += 256) { cnt[t] = 0; flushed[t] = 0; }
    __syncthreads();

    const int per = (n_edges + PH1B - 1) / PH1B;
    const int begin = blockIdx.x * per;
    const int end = min(begin + per, n_edges);

    for (int base = begin; base < end; base += 256) {
        int i = base + tid;
        if (i < end) {
            int s = src[i], d = dst[i];
            int b = d >> 6;
            unsigned rec = (unsigned)s | ((unsigned)(d & 63) << 16);
            int pos = atomicAdd(&cnt[b], 1);
            buf[b][pos & (RING - 1)] = rec;
        }
        __syncthreads();
        for (int t = tid; t < NBINS; t += 256) {
            int c = cnt[t];
            int f = flushed[t];
            while (c - f >= 16) {                    // 16 recs = 64B = 1 line
                int gbase = atomicAdd(&bcnt[t], 16);
                unsigned* dp = recs + (long)t * CAPG + gbase;
                int ro = f & (RING - 1);             // multiple of 16, no wrap
                #pragma unroll
                for (int k = 0; k < 4; ++k)
                    *(uint4*)(dp + k * 4) = *(uint4*)&buf[t][ro + k * 4];
                f += 16;
            }
            flushed[t] = f;
        }
        __syncthreads();
    }
    for (int t = tid; t < NBINS; t += 256) {
        int c = cnt[t], f = flushed[t];
        int n = c - f;
        if (n > 0) {
            int gbase = atomicAdd(&bcnt[t], n);
            unsigned* dp = recs + (long)t * CAPG + gbase;
            int ro = f & (RING - 1);
            for (int k = 0; k < n; ++k) dp[k] = buf[t][ro + k];
        }
    }
}

// ---------------- 2. FUSED per-bin aggregate + MLP + BN (512 thr / 8 waves) ----------------
// Same per-bin work as R9 but 8 waves: gather wave owns 8 nodes; MLP wave
// (m = w&3, ch = w>>2) owns M-tile m (16 rows) x 64-col half ch.
// Extra barrier between stage-1 reads and x2 writes (cross-wave row sharing).
__global__ __launch_bounds__(512, 6)
void agg_mlp_kernel(const unsigned* __restrict__ xb2, const unsigned* __restrict__ recs,
                    const int* __restrict__ bcnt, const unsigned short* __restrict__ wb,
                    const float* __restrict__ brel, const float* __restrict__ blin,
                    float* __restrict__ out, float* __restrict__ sums,
                    float* __restrict__ sumsq)
{
    __shared__ unsigned srec[CAPG];                       // 16 KB (later: BN scratch)
    __shared__ int cnt[BINSZ];
    __shared__ int pos[BINSZ];
    __shared__ int offs[BINSZ + 1];
    __shared__ __align__(16) unsigned short smA[BINSZ][136];  // 17.4 KB

    const int bin = blockIdx.x;
    const int tid = threadIdx.x;          // 0..511
    const int l = tid & 63, w = tid >> 6; // wave 0..7
    const int l15 = l & 15, kg = l >> 4;
    const int g16 = l >> 4, c16 = l & 15; // gather: record slot / row chunk

    if (tid < BINSZ) cnt[tid] = 0;
    __syncthreads();

    const int n = bcnt[bin];
    const unsigned* rp = recs + (long)bin * CAPG;

    // A1: histogram by local dst
    for (int i = tid; i < n; i += 512)
        atomicAdd(&cnt[(rp[i] >> 16) & 63], 1);
    __syncthreads();

    // A2: exclusive scan over 64 counters (wave 0)
    if (tid < 64) {
        int v = cnt[tid];
        int inc = v;
        #pragma unroll
        for (int d = 1; d < 64; d <<= 1) {
            int u = __shfl_up(inc, d);
            if (tid >= d) inc += u;
        }
        offs[tid] = inc - v;
        pos[tid] = inc - v;
        if (tid == 63) offs[64] = inc;
    }
    __syncthreads();

    // A3: scatter into sorted order
    for (int i = tid; i < n; i += 512) {
        unsigned r = rp[i];
        int p = atomicAdd(&pos[(r >> 16) & 63], 1);
        srec[p] = r;
    }
    __syncthreads();

    // A4: per-node register accumulation, uint4 gather (4 records/load)
    unsigned* smA32 = (unsigned*)smA;
    for (int lo = w; lo < BINSZ; lo += 8) {
        const int b = offs[lo], e = offs[lo + 1];
        float c[8];
        #pragma unroll
        for (int k = 0; k < 8; ++k) c[k] = 0.f;

        int i = b;
        for (; i + 16 <= e; i += 16) {
            unsigned r0 = srec[i + g16];
            unsigned r1 = srec[i + 4 + g16];
            unsigned r2 = srec[i + 8 + g16];
            unsigned r3 = srec[i + 12 + g16];
            uint4 q0 = *((const uint4*)(xb2 + (r0 & 0xffffu) * 64) + c16);
            uint4 q1 = *((const uint4*)(xb2 + (r1 & 0xffffu) * 64) + c16);
            uint4 q2 = *((const uint4*)(xb2 + (r2 & 0xffffu) * 64) + c16);
            uint4 q3 = *((const uint4*)(xb2 + (r3 & 0xffffu) * 64) + c16);
            acc8(c, q0); acc8(c, q1); acc8(c, q2); acc8(c, q3);
        }
        for (; i + 4 <= e; i += 4) {
            unsigned r = srec[i + g16];
            uint4 q = *((const uint4*)(xb2 + (r & 0xffffu) * 64) + c16);
            acc8(c, q);
        }
        if (i < e) {                                   // 1..3 leftover records
            int idx = i + g16;
            unsigned r = srec[idx < e ? idx : e - 1];
            if (idx < e) {
                uint4 q = *((const uint4*)(xb2 + (r & 0xffffu) * 64) + c16);
                acc8(c, q);
            }
        }
        // fold the 4 record slots
        #pragma unroll
        for (int k = 0; k < 8; ++k) {
            c[k] += __shfl_xor(c[k], 16);
            c[k] += __shfl_xor(c[k], 32);
        }
        if (l < 16) {
            uint4 o;
            o.x = packbf(c[0], c[1]); o.y = packbf(c[2], c[3]);
            o.z = packbf(c[4], c[5]); o.w = packbf(c[6], c[7]);
            *((uint4*)(smA32 + lo * 68) + c16) = o;
        }
    }
    __syncthreads();   // smA ready; srec reads complete (free for reuse)

    // ---- Phase B: MLP ----
    const unsigned short* Wrelb  = wb;
    const unsigned short* Wrootb = wb + 16384;
    const unsigned short* Wlinb  = wb + 32768;
    const unsigned short* xbs = (const unsigned short*)xb2;

    const int m  = w & 3;                 // M-tile (16 rows)
    const int ch = w >> 2;                // column half (64 cols)
    const int row = m * 16 + l15;         // A-frag node row (local)
    const int gA = bin * 64 + row;
    const long gAc = min(gA, NNODES - 1);

    f32x4 acc[4];
    #pragma unroll
    for (int nt = 0; nt < 4; ++nt) acc[nt] = (f32x4){0.f, 0.f, 0.f, 0.f};

    #pragma unroll
    for (int s = 0; s < 8; ++s) {
        const int ko = (s & 3) * 32 + kg * 8;
        bf16x8 a;
        if (s < 4) a = *(const bf16x8*)&smA[row][ko];
        else       a = *(const bf16x8*)(xbs + gAc * 128 + ko);
        const unsigned short* Bb = (s < 4) ? Wrelb : Wrootb;
        #pragma unroll
        for (int nt = 0; nt < 4; ++nt) {
            bf16x8 b = *(const bf16x8*)(Bb + (ch * 64 + nt * 16 + l15) * 128 + ko);
            acc[nt] = __builtin_amdgcn_mfma_f32_16x16x32_bf16(a, b, acc[nt], 0, 0, 0);
        }
    }
    __syncthreads();   // stage-1 smA reads done before cross-wave x2 writes

    // x2 = lrelu(acc + brel) -> smA rows m*16.., cols ch*64..
    #pragma unroll
    for (int nt = 0; nt < 4; ++nt) {
        const int col = ch * 64 + nt * 16 + l15;
        const float br = brel[col];
        #pragma unroll
        for (int r = 0; r < 4; ++r) {
            smA[m * 16 + kg * 4 + r][col] =
                (unsigned short)f2bf(lrelu(acc[nt][r] + br));
        }
    }
    __syncthreads();

    f32x4 acc2[4];
    #pragma unroll
    for (int nt = 0; nt < 4; ++nt) acc2[nt] = (f32x4){0.f, 0.f, 0.f, 0.f};

    #pragma unroll
    for (int s = 0; s < 4; ++s) {
        const int ko = s * 32 + kg * 8;
        bf16x8 a = *(const bf16x8*)&smA[row][ko];
        #pragma unroll
        for (int nt = 0; nt < 4; ++nt) {
            bf16x8 b = *(const bf16x8*)(Wlinb + (ch * 64 + nt * 16 + l15) * 128 + ko);
            acc2[nt] = __builtin_amdgcn_mfma_f32_16x16x32_bf16(a, b, acc2[nt], 0, 0, 0);
        }
    }

    // epilogue: +blin, store fp32, BN partials via LDS (srec as scratch)
    float* redS = (float*)srec;   // [2 kinds][4 m][128 cols] = 4 KB
    #pragma unroll
    for (int nt = 0; nt < 4; ++nt) {
        const int col = ch * 64 + nt * 16 + l15;
        const float bl = blin[col];
        float ps = 0.f, pq = 0.f;
        #pragma unroll
        for (int r = 0; r < 4; ++r) {
            int g = bin * 64 + m * 16 + kg * 4 + r;
            if (g < NNODES) {
                float y = acc2[nt][r] + bl;
                out[(long)g * 128 + col] = y;
                ps += y; pq += y * y;
            }
        }
        ps += __shfl_xor(ps, 16); ps += __shfl_xor(ps, 32);
        pq += __shfl_xor(pq, 16); pq += __shfl_xor(pq, 32);
        if (kg == 0) {
            redS[(0 * 4 + m) * 128 + col] = ps;
            redS[(1 * 4 + m) * 128 + col] = pq;
        }
    }
    __syncthreads();
    if (tid < 128) {
        float s = redS[0 * 128 + tid] + redS[1 * 128 + tid]
                + redS[2 * 128 + tid] + redS[3 * 128 + tid];
        float q = redS[4 * 128 + tid] + redS[5 * 128 + tid]
                + redS[6 * 128 + tid] + redS[7 * 128 + tid];
        atomicAdd(&sums[tid], s);
        atomicAdd(&sumsq[tid], q);
    }
}

// ---------------- 3. BN finalize ----------------
__global__ void bn_final_kernel(const float* __restrict__ sums, const float* __restrict__ sumsq,
                                const float* __restrict__ gamma, const float* __restrict__ beta,
                                float* __restrict__ ss)
{
    int h = threadIdx.x;
    float mean = sums[h] * (1.f / NNODES);
    float var = sumsq[h] * (1.f / NNODES) - mean * mean;
    float sc = gamma[h] * rsqrtf(var + BN_EPS);
    ss[h] = sc;
    ss[128 + h] = beta[h] - mean * sc;
}

// ---------------- 4. BN apply + leaky (in-place fp32) ----------------
__global__ __launch_bounds__(256)
void bn_apply_kernel(float* __restrict__ out, const float* __restrict__ ss)
{
    __shared__ float s_sc[128], s_sh[128];
    if (threadIdx.x < 128) {
        s_sc[threadIdx.x] = ss[threadIdx.x];
        s_sh[threadIdx.x] = ss[128 + threadIdx.x];
    }
    __syncthreads();
    const int total = NNODES * 32;
    float4* o4 = (float4*)out;
    for (int i = blockIdx.x * 256 + threadIdx.x; i < total; i += gridDim.x * 256) {
        float4 v = o4[i];
        int h = (i & 31) * 4;
        v.x = lrelu(v.x * s_sc[h + 0] + s_sh[h + 0]);
        v.y = lrelu(v.y * s_sc[h + 1] + s_sh[h + 1]);
        v.z = lrelu(v.z * s_sc[h + 2] + s_sh[h + 2]);
        v.w = lrelu(v.w * s_sc[h + 3] + s_sh[h + 3]);
        o4[i] = v;
    }
}

extern "C" void kernel_launch(void* const* d_in, const int* in_sizes, int n_in,
                              void* d_out, int out_size, void* d_ws, size_t ws_size,
                              hipStream_t stream)
{
    const float* x     = (const float*)d_in[0];
    const int*   ei    = (const int*)d_in[1];
    const float* Wrel  = (const float*)d_in[3];
    const float* brel  = (const float*)d_in[4];
    const float* Wroot = (const float*)d_in[5];
    const float* Wlin  = (const float*)d_in[6];
    const float* blin  = (const float*)d_in[7];
    const float* gamma = (const float*)d_in[8];
    const float* beta  = (const float*)d_in[9];
    float* out = (float*)d_out;

    const int n_edges = in_sizes[1] / 2;
    const int* src = ei;
    const int* dst = ei + n_edges;

    // workspace layout (bytes):
    // xb    @ 0          : 12,800,000   (x as bf16)
    // recs  @ 12,800,000 : 12,812,288   (NBINS*CAPG*4)
    // wb    @ 25,612,288 : 98,304
    // bcnt  @ 25,710,592 : 3,128        } memset together (5,248 B)
    // stats @ 25,713,792 : 2,048        }   -> total 25.72 MB
    char* ws = (char*)d_ws;
    unsigned short* xb   = (unsigned short*)ws;
    unsigned*       recs = (unsigned*)(ws + 12800000);
    unsigned short* wb   = (unsigned short*)(ws + 25612288);
    int*   bcnt  = (int*)(ws + 25710592);
    float* sums  = (float*)(ws + 25713792);
    float* sumsq = sums + 128;
    float* ss    = sums + 256;

    hipMemsetAsync(bcnt, 0, 5248, stream);   // bcnt + stats

    prep_kernel<<<4096, 256, 0, stream>>>(x, Wrel, Wroot, Wlin, (unsigned*)xb, (unsigned*)wb);
    bin_kernel<<<PH1B, 256, 0, stream>>>(src, dst, bcnt, recs, n_edges);
    agg_mlp_kernel<<<NBINS, 512, 0, stream>>>((const unsigned*)xb, recs, bcnt, wb,
                                              brel, blin, out, sums, sumsq);
    bn_final_kernel<<<1, 128, 0, stream>>>(sums, sumsq, gamma, beta, ss);
    bn_apply_kernel<<<2048, 256, 0, stream>>>(out, ss);
}